// Round 1
// baseline (695.251 us; speedup 1.0000x reference)
//
#include <hip/hip_runtime.h>

typedef unsigned short u16;
typedef __attribute__((ext_vector_type(8))) short bf16x8;
typedef __attribute__((ext_vector_type(4))) float f32x4;
typedef __attribute__((ext_vector_type(4))) unsigned short u16x4;

#define S_LEN 2048
#define HIDDEN 2048
#define NHEAD 16
#define QLORA 1536
#define KVLORA 512
#define NOPE_D 128
#define ROPE_D 64
#define V_D 128
#define HEAD_D 192

// SOFTMAX_SCALE = 192^-0.5 * mscale^2, mscale = 0.1*ln(40)+1
__device__ __constant__ float SM_SCALE_C = (float)(0.07216878364870323 *
    ((0.1 * 3.6888794541139363 + 1.0) * (0.1 * 3.6888794541139363 + 1.0)));

__device__ inline u16 f2bf(float f) {
    union { float f; unsigned int u; } v; v.f = f;
    unsigned int r = v.u + 0x7FFFu + ((v.u >> 16) & 1u);
    return (u16)(r >> 16);
}

// ---------------- f32 -> bf16 convert ----------------
__global__ void cvt_f32_bf16(const float* __restrict__ in, u16* __restrict__ out, int n) {
    int i = (blockIdx.x * blockDim.x + threadIdx.x) * 4;
    if (i >= n) return;
    f32x4 v = *(const f32x4*)(in + i);
    u16x4 o;
    o[0] = f2bf(v[0]); o[1] = f2bf(v[1]); o[2] = f2bf(v[2]); o[3] = f2bf(v[3]);
    *(u16x4*)(out + i) = o;
}

// ---------------- rmsnorm: f32 in (strided), bf16 out ----------------
__global__ __launch_bounds__(256)
void rmsnorm_k(const float* __restrict__ in, const float* __restrict__ w,
               u16* __restrict__ out, int D, int istride, int ostride) {
    int row = blockIdx.x;
    const float* x = in + (size_t)row * istride;
    float ss = 0.f;
    for (int d = threadIdx.x; d < D; d += 256) { float v = x[d]; ss += v * v; }
    #pragma unroll
    for (int off = 1; off < 64; off <<= 1) ss += __shfl_xor(ss, off, 64);
    __shared__ float red[4];
    if ((threadIdx.x & 63) == 0) red[threadIdx.x >> 6] = ss;
    __syncthreads();
    float tot = red[0] + red[1] + red[2] + red[3];
    float rs = rsqrtf(tot / (float)D + 1e-6f);
    for (int d = threadIdx.x; d < D; d += 256)
        out[(size_t)row * ostride + d] = f2bf(x[d] * rs * w[d]);
}

// ---------------- generic dequant GEMM: C[M,N] = A(bf16)[M,K] @ (W*s)^T ----------------
// W: f32 [N,K], scales: f32 [ceil(N/128), sc_cols], block 128x128
__global__ __launch_bounds__(256)
void gemm_dq(const u16* __restrict__ A, const float* __restrict__ W,
             const float* __restrict__ Sc, float* __restrict__ C,
             int M, int N, int K, int sc_cols) {
    __shared__ u16 As[128][56];
    __shared__ u16 Ws[128][56];
    const int tid = threadIdx.x;
    const int lane = tid & 63;
    const int wv = tid >> 6;
    const int wm = wv >> 1, wn = wv & 1;
    const int bm = blockIdx.y * 128, bn = blockIdx.x * 128;
    const int lr = lane & 15, lk = lane >> 4;

    const int srow = tid >> 1;
    const int scol = (tid & 1) * 16;

    f32x4 acc[4][4] = {};

    for (int k0 = 0; k0 < K; k0 += 32) {
        __syncthreads();
        // stage A tile (bf16 passthrough)
        {
            const u16* ap = A + (size_t)(bm + srow) * K + k0 + scol;
            bf16x8 a0 = *(const bf16x8*)ap;
            bf16x8 a1 = *(const bf16x8*)(ap + 8);
            *(bf16x8*)&As[srow][scol] = a0;
            *(bf16x8*)&As[srow][scol + 8] = a1;
        }
        // stage W tile with fused dequant f32*scale -> bf16
        {
            int n = bn + srow;
            bf16x8 w0, w1;
            if (n < N) {
                float sc = Sc[(n >> 7) * sc_cols + (k0 >> 7)];
                const float* wp = W + (size_t)n * K + k0 + scol;
                f32x4 v0 = *(const f32x4*)(wp);
                f32x4 v1 = *(const f32x4*)(wp + 4);
                f32x4 v2 = *(const f32x4*)(wp + 8);
                f32x4 v3 = *(const f32x4*)(wp + 12);
                #pragma unroll
                for (int i = 0; i < 4; ++i) {
                    w0[i]     = (short)f2bf(v0[i] * sc);
                    w0[i + 4] = (short)f2bf(v1[i] * sc);
                    w1[i]     = (short)f2bf(v2[i] * sc);
                    w1[i + 4] = (short)f2bf(v3[i] * sc);
                }
            } else {
                w0 = (bf16x8)(short)0; w1 = (bf16x8)(short)0;
            }
            *(bf16x8*)&Ws[srow][scol] = w0;
            *(bf16x8*)&Ws[srow][scol + 8] = w1;
        }
        __syncthreads();
        // compute
        bf16x8 af[4], bfr[4];
        #pragma unroll
        for (int mi = 0; mi < 4; ++mi)
            af[mi] = *(const bf16x8*)&As[wm * 64 + mi * 16 + lr][lk * 8];
        #pragma unroll
        for (int ni = 0; ni < 4; ++ni)
            bfr[ni] = *(const bf16x8*)&Ws[wn * 64 + ni * 16 + lr][lk * 8];
        #pragma unroll
        for (int mi = 0; mi < 4; ++mi)
            #pragma unroll
            for (int ni = 0; ni < 4; ++ni)
                acc[mi][ni] = __builtin_amdgcn_mfma_f32_16x16x32_bf16(af[mi], bfr[ni], acc[mi][ni], 0, 0, 0);
    }

    #pragma unroll
    for (int mi = 0; mi < 4; ++mi)
        #pragma unroll
        for (int ni = 0; ni < 4; ++ni)
            #pragma unroll
            for (int j = 0; j < 4; ++j) {
                int r = bm + wm * 64 + mi * 16 + lk * 4 + j;
                int c = bn + wn * 64 + ni * 16 + lr;
                if (c < N) C[(size_t)r * N + c] = acc[mi][ni][j];
            }
}

// ---------------- q prep: split nope/pe, RoPE pe, scale, -> bf16 [S][NH][192] ----------------
__global__ void prep_q(const float* __restrict__ q, const float* __restrict__ cosb,
                       const float* __restrict__ sinb, u16* __restrict__ qf) {
    int s = blockIdx.x;
    int d = threadIdx.x; // 192 threads
    float sm = SM_SCALE_C;
    for (int h = 0; h < NHEAD; ++h) {
        const float* qp = q + (size_t)s * (NHEAD * HEAD_D) + h * HEAD_D;
        float val;
        if (d < NOPE_D) {
            val = qp[d];
        } else {
            int r = d - NOPE_D;
            float x = qp[d];
            float rot = (r < 32) ? -qp[NOPE_D + r + 32] : qp[NOPE_D + r - 32];
            val = x * cosb[s * ROPE_D + r] + rot * sinb[s * ROPE_D + r];
        }
        qf[((size_t)s * NHEAD + h) * HEAD_D + d] = f2bf(val * sm);
    }
}

// ---------------- kv prep: k_full bf16 [S][NH][192], v^T bf16 [NH][128][S] ----------------
__global__ void prep_kv(const float* __restrict__ kvb, const float* __restrict__ lkv,
                        const float* __restrict__ cosb, const float* __restrict__ sinb,
                        u16* __restrict__ kf, u16* __restrict__ vt) {
    int s = blockIdx.x;
    int d = threadIdx.x; // 192 threads
    float kpe = 0.f;
    if (d >= NOPE_D) {
        int r = d - NOPE_D;
        const float* kp = lkv + (size_t)s * (KVLORA + ROPE_D) + KVLORA;
        float x = kp[r];
        float rot = (r < 32) ? -kp[r + 32] : kp[r - 32];
        kpe = x * cosb[s * ROPE_D + r] + rot * sinb[s * ROPE_D + r];
    }
    for (int h = 0; h < NHEAD; ++h) {
        const float* kvp = kvb + (size_t)s * (NHEAD * 256) + h * 256;
        float val = (d < NOPE_D) ? kvp[d] : kpe;
        kf[((size_t)s * NHEAD + h) * HEAD_D + d] = f2bf(val);
        if (d < V_D)
            vt[((size_t)(h * V_D + d)) * S_LEN + s] = f2bf(kvp[NOPE_D + d]);
    }
}

// ---------------- causal flash attention ----------------
// q_full/k_full: bf16 [S][NH][192] (q pre-scaled); vt: bf16 [NH][128][S]
// out attn: bf16 [S][NH*128]
__global__ __launch_bounds__(256)
void flash_attn(const u16* __restrict__ qf, const u16* __restrict__ kf,
                const u16* __restrict__ vt, u16* __restrict__ attn) {
    __shared__ u16 Pb[4][16][40];
    const int tid = threadIdx.x, lane = tid & 63, wv = tid >> 6;
    const int h = blockIdx.y;
    const int q0 = blockIdx.x * 64 + wv * 16;
    const int lr = lane & 15, lk = lane >> 4;

    bf16x8 qfrag[6];
    #pragma unroll
    for (int kk = 0; kk < 6; ++kk)
        qfrag[kk] = *(const bf16x8*)&qf[((size_t)(q0 + lr) * NHEAD + h) * HEAD_D + kk * 32 + lk * 8];

    f32x4 o[8] = {};
    float m[4], l[4];
    #pragma unroll
    for (int j = 0; j < 4; ++j) { m[j] = -3.0e38f; l[j] = 0.f; }

    for (int kv0 = 0; kv0 <= q0 + 15; kv0 += 32) {
        f32x4 s0 = {}, s1 = {};
        #pragma unroll
        for (int kk = 0; kk < 6; ++kk) {
            bf16x8 kb0 = *(const bf16x8*)&kf[((size_t)(kv0 + lr) * NHEAD + h) * HEAD_D + kk * 32 + lk * 8];
            bf16x8 kb1 = *(const bf16x8*)&kf[((size_t)(kv0 + 16 + lr) * NHEAD + h) * HEAD_D + kk * 32 + lk * 8];
            s0 = __builtin_amdgcn_mfma_f32_16x16x32_bf16(qfrag[kk], kb0, s0, 0, 0, 0);
            s1 = __builtin_amdgcn_mfma_f32_16x16x32_bf16(qfrag[kk], kb1, s1, 0, 0, 0);
        }
        if (kv0 + 31 > q0) { // masking needed on (part of) this tile
            #pragma unroll
            for (int j = 0; j < 4; ++j) {
                int row = q0 + lk * 4 + j;
                if (kv0 + lr > row)      s0[j] = -3.0e38f;
                if (kv0 + 16 + lr > row) s1[j] = -3.0e38f;
            }
        }
        float sc[4], pr0[4], pr1[4];
        #pragma unroll
        for (int j = 0; j < 4; ++j) {
            float tm = fmaxf(s0[j], s1[j]);
            #pragma unroll
            for (int off = 1; off < 16; off <<= 1) tm = fmaxf(tm, __shfl_xor(tm, off, 64));
            float mn = fmaxf(m[j], tm);
            float scale = exp2f((m[j] - mn) * 1.442695041f);
            pr0[j] = exp2f((s0[j] - mn) * 1.442695041f);
            pr1[j] = exp2f((s1[j] - mn) * 1.442695041f);
            float psum = pr0[j] + pr1[j];
            #pragma unroll
            for (int off = 1; off < 16; off <<= 1) psum += __shfl_xor(psum, off, 64);
            l[j] = l[j] * scale + psum;
            m[j] = mn;
            sc[j] = scale;
        }
        #pragma unroll
        for (int vd = 0; vd < 8; ++vd)
            #pragma unroll
            for (int j = 0; j < 4; ++j) o[vd][j] *= sc[j];
        // transpose P into A-fragment layout via per-wave LDS
        #pragma unroll
        for (int j = 0; j < 4; ++j) {
            Pb[wv][lk * 4 + j][lr] = f2bf(pr0[j]);
            Pb[wv][lk * 4 + j][16 + lr] = f2bf(pr1[j]);
        }
        asm volatile("s_waitcnt lgkmcnt(0)" ::: "memory");
        bf16x8 pa = *(const bf16x8*)&Pb[wv][lr][lk * 8];
        #pragma unroll
        for (int vd = 0; vd < 8; ++vd) {
            bf16x8 vb = *(const bf16x8*)&vt[((size_t)(h * V_D + vd * 16 + lr)) * S_LEN + kv0 + lk * 8];
            o[vd] = __builtin_amdgcn_mfma_f32_16x16x32_bf16(pa, vb, o[vd], 0, 0, 0);
        }
    }

    float inv[4];
    #pragma unroll
    for (int j = 0; j < 4; ++j) inv[j] = 1.0f / l[j];
    #pragma unroll
    for (int vd = 0; vd < 8; ++vd)
        #pragma unroll
        for (int j = 0; j < 4; ++j) {
            int row = q0 + lk * 4 + j;
            attn[(size_t)row * (NHEAD * V_D) + h * V_D + vd * 16 + lr] = f2bf(o[vd][j] * inv[j]);
        }
}

extern "C" void kernel_launch(void* const* d_in, const int* in_sizes, int n_in,
                              void* d_out, int out_size, void* d_ws, size_t ws_size,
                              hipStream_t stream) {
    const float* hs    = (const float*)d_in[0];
    const float* wq_a  = (const float*)d_in[1];
    const float* sq_a  = (const float*)d_in[2];
    const float* wq_b  = (const float*)d_in[3];
    const float* sq_b  = (const float*)d_in[4];
    const float* wkv_a = (const float*)d_in[5];
    const float* skv_a = (const float*)d_in[6];
    const float* wkv_b = (const float*)d_in[7];
    const float* skv_b = (const float*)d_in[8];
    const float* wo    = (const float*)d_in[9];
    const float* so    = (const float*)d_in[10];
    const float* q_ln  = (const float*)d_in[11];
    const float* kv_ln = (const float*)d_in[12];
    const float* cosb  = (const float*)d_in[13];
    const float* sinb  = (const float*)d_in[14];
    float* out = (float*)d_out;

    char* ws = (char*)d_ws;
    size_t off = 0;
    auto alloc = [&](size_t bytes) -> void* {
        void* p = ws + off; off += (bytes + 255) & ~(size_t)255; return p;
    };
    u16*   hs_bf  = (u16*)  alloc((size_t)S_LEN * HIDDEN * 2);
    float* lq     = (float*)alloc((size_t)S_LEN * QLORA * 4);
    u16*   lqn    = (u16*)  alloc((size_t)S_LEN * QLORA * 2);
    float* qf32   = (float*)alloc((size_t)S_LEN * NHEAD * HEAD_D * 4);
    u16*   q_full = (u16*)  alloc((size_t)S_LEN * NHEAD * HEAD_D * 2);
    float* lkv    = (float*)alloc((size_t)S_LEN * (KVLORA + ROPE_D) * 4);
    u16*   kvn    = (u16*)  alloc((size_t)S_LEN * KVLORA * 2);
    float* kvb    = (float*)alloc((size_t)S_LEN * NHEAD * 256 * 4);
    u16*   k_full = (u16*)  alloc((size_t)S_LEN * NHEAD * HEAD_D * 2);
    u16*   vt     = (u16*)  alloc((size_t)NHEAD * V_D * S_LEN * 2);
    u16*   attn   = (u16*)  alloc((size_t)S_LEN * NHEAD * V_D * 2);

    cvt_f32_bf16<<<(S_LEN * HIDDEN / 4 + 255) / 256, 256, 0, stream>>>(hs, hs_bf, S_LEN * HIDDEN);

    // lq = hs @ dq(wq_a)^T   [2048 x 1536]
    gemm_dq<<<dim3(QLORA / 128, S_LEN / 128), 256, 0, stream>>>(hs_bf, wq_a, sq_a, lq,
        S_LEN, QLORA, HIDDEN, 16);
    rmsnorm_k<<<S_LEN, 256, 0, stream>>>(lq, q_ln, lqn, QLORA, QLORA, QLORA);
    // q = rms(lq) @ dq(wq_b)^T  [2048 x 3072]
    gemm_dq<<<dim3(NHEAD * HEAD_D / 128, S_LEN / 128), 256, 0, stream>>>(lqn, wq_b, sq_b, qf32,
        S_LEN, NHEAD * HEAD_D, QLORA, 12);
    // lkv = hs @ dq(wkv_a)^T  [2048 x 576]
    gemm_dq<<<dim3(5, S_LEN / 128), 256, 0, stream>>>(hs_bf, wkv_a, skv_a, lkv,
        S_LEN, KVLORA + ROPE_D, HIDDEN, 16);
    rmsnorm_k<<<S_LEN, 256, 0, stream>>>(lkv, kv_ln, kvn, KVLORA, KVLORA + ROPE_D, KVLORA);
    // kvb = kv_nope @ dq(wkv_b)^T  [2048 x 4096]
    gemm_dq<<<dim3(NHEAD * 256 / 128, S_LEN / 128), 256, 0, stream>>>(kvn, wkv_b, skv_b, kvb,
        S_LEN, NHEAD * 256, KVLORA, 4);

    prep_q<<<S_LEN, 192, 0, stream>>>(qf32, cosb, sinb, q_full);
    prep_kv<<<S_LEN, 192, 0, stream>>>(kvb, lkv, cosb, sinb, k_full, vt);

    flash_attn<<<dim3(S_LEN / 64, NHEAD), 256, 0, stream>>>(q_full, k_full, vt, attn);

    // out = attn @ dq(wo)^T  [2048 x 2048]
    gemm_dq<<<dim3(HIDDEN / 128, S_LEN / 128), 256, 0, stream>>>(attn, wo, so, out,
        S_LEN, HIDDEN, NHEAD * V_D, 16);
}

// Round 2
// 476.194 us; speedup vs baseline: 1.4600x; 1.4600x over previous
//
#include <hip/hip_runtime.h>

typedef unsigned short u16;
typedef __attribute__((ext_vector_type(8))) short bf16x8;
typedef __attribute__((ext_vector_type(4))) float f32x4;
typedef __attribute__((ext_vector_type(4))) unsigned short u16x4;

#define S_LEN 2048
#define HIDDEN 2048
#define NHEAD 16
#define QLORA 1536
#define KVLORA 512
#define NOPE_D 128
#define ROPE_D 64
#define V_D 128
#define HEAD_D 192
#define LOG2E 1.442695041f

// SOFTMAX_SCALE = 192^-0.5 * mscale^2, mscale = 0.1*ln(40)+1
__device__ __constant__ float SM_SCALE_C = (float)(0.07216878364870323 *
    ((0.1 * 3.6888794541139363 + 1.0) * (0.1 * 3.6888794541139363 + 1.0)));

__device__ inline u16 f2bf(float f) {
    union { float f; unsigned int u; } v; v.f = f;
    unsigned int r = v.u + 0x7FFFu + ((v.u >> 16) & 1u);
    return (u16)(r >> 16);
}
__device__ inline float bf2f(u16 b) {
    union { unsigned int u; float f; } v; v.u = ((unsigned int)b) << 16;
    return v.f;
}
__device__ inline void gload_lds16(const u16* g, u16* l) {
    __builtin_amdgcn_global_load_lds(
        (const __attribute__((address_space(1))) void*)g,
        (__attribute__((address_space(3))) void*)l, 16, 0, 0);
}

// ---------------- f32 -> bf16 convert ----------------
__global__ void cvt_f32_bf16(const float* __restrict__ in, u16* __restrict__ out, int n) {
    int i = (blockIdx.x * blockDim.x + threadIdx.x) * 4;
    if (i >= n) return;
    f32x4 v = *(const f32x4*)(in + i);
    u16x4 o;
    o[0] = f2bf(v[0]); o[1] = f2bf(v[1]); o[2] = f2bf(v[2]); o[3] = f2bf(v[3]);
    *(u16x4*)(out + i) = o;
}

// ---------------- weight dequant: f32 [N,K] * blockscale -> bf16 [Npad,K] ----------------
__global__ __launch_bounds__(64)
void dequant_w(const float* __restrict__ W, const float* __restrict__ Sc,
               u16* __restrict__ out, int N, int K, int sc_cols) {
    int k = (blockIdx.x * 64 + threadIdx.x) * 8;
    int n = blockIdx.y;
    if (k >= K) return;
    float sc = Sc[(n >> 7) * sc_cols + (k >> 7)];
    f32x4 v0 = *(const f32x4*)(W + (size_t)n * K + k);
    f32x4 v1 = *(const f32x4*)(W + (size_t)n * K + k + 4);
    bf16x8 o;
    #pragma unroll
    for (int i = 0; i < 4; ++i) {
        o[i]     = (short)f2bf(v0[i] * sc);
        o[i + 4] = (short)f2bf(v1[i] * sc);
    }
    *(bf16x8*)(out + (size_t)n * K + k) = o;
}

// ---------------- rmsnorm: bf16 in (strided), bf16 out ----------------
__global__ __launch_bounds__(256)
void rmsnorm_k(const u16* __restrict__ in, const float* __restrict__ w,
               u16* __restrict__ out, int D, int istride, int ostride) {
    int row = blockIdx.x;
    const u16* x = in + (size_t)row * istride;
    float ss = 0.f;
    for (int d = threadIdx.x; d < D; d += 256) { float v = bf2f(x[d]); ss += v * v; }
    #pragma unroll
    for (int off = 1; off < 64; off <<= 1) ss += __shfl_xor(ss, off, 64);
    __shared__ float red[4];
    if ((threadIdx.x & 63) == 0) red[threadIdx.x >> 6] = ss;
    __syncthreads();
    float tot = red[0] + red[1] + red[2] + red[3];
    float rs = rsqrtf(tot / (float)D + 1e-6f);
    for (int d = threadIdx.x; d < D; d += 256)
        out[(size_t)row * ostride + d] = f2bf(bf2f(x[d]) * rs * w[d]);
}

// ---------------- bf16 GEMM (m97 structure): C[M,N] = A[M,K] @ W[N,K]^T ----------------
// A: bf16 [M,K]; W: bf16 [>=N,K] (rows beyond N may be garbage, never stored)
// out: f32 if obf==0 else bf16
__global__ __launch_bounds__(256)
void gemm_bf16(const u16* __restrict__ A, const u16* __restrict__ W,
               void* __restrict__ C, int M, int N, int K, int obf) {
    __shared__ u16 As[128 * 64];
    __shared__ u16 Ws[128 * 64];
    const int tid = threadIdx.x;
    const int lane = tid & 63;
    const int wv = tid >> 6;
    const int wm = wv >> 1, wn = wv & 1;
    const int bm = blockIdx.y * 128, bn = blockIdx.x * 128;
    const int lr = lane & 15, lk = lane >> 4;
    const int srow = lane >> 3;      // 0..7 within 8-row stripe
    const int schunk = lane & 7;     // 16B chunk within row

    f32x4 acc[4][4] = {};

    for (int k0 = 0; k0 < K; k0 += 64) {
        __syncthreads();
        #pragma unroll
        for (int i = 0; i < 4; ++i) {
            int t = (wv * 4 + i) * 8 + srow;                 // tile row 0..127
            int cs = (schunk ^ (t & 7)) << 3;                // swizzled k-chunk (elems)
            gload_lds16(A + (size_t)(bm + t) * K + k0 + cs, &As[(wv * 4 + i) * 512]);
            gload_lds16(W + (size_t)(bn + t) * K + k0 + cs, &Ws[(wv * 4 + i) * 512]);
        }
        __syncthreads();
        #pragma unroll
        for (int kh = 0; kh < 2; ++kh) {
            bf16x8 af[4], bfr[4];
            #pragma unroll
            for (int mi = 0; mi < 4; ++mi) {
                int r = wm * 64 + mi * 16 + lr;
                af[mi] = *(const bf16x8*)&As[r * 64 + (((kh * 4 + lk) ^ (lr & 7)) << 3)];
            }
            #pragma unroll
            for (int ni = 0; ni < 4; ++ni) {
                int r = wn * 64 + ni * 16 + lr;
                bfr[ni] = *(const bf16x8*)&Ws[r * 64 + (((kh * 4 + lk) ^ (lr & 7)) << 3)];
            }
            #pragma unroll
            for (int mi = 0; mi < 4; ++mi)
                #pragma unroll
                for (int ni = 0; ni < 4; ++ni)
                    acc[mi][ni] = __builtin_amdgcn_mfma_f32_16x16x32_bf16(af[mi], bfr[ni], acc[mi][ni], 0, 0, 0);
        }
    }

    #pragma unroll
    for (int mi = 0; mi < 4; ++mi)
        #pragma unroll
        for (int ni = 0; ni < 4; ++ni)
            #pragma unroll
            for (int j = 0; j < 4; ++j) {
                int r = bm + wm * 64 + mi * 16 + lk * 4 + j;
                int c = bn + wn * 64 + ni * 16 + lr;
                if (c < N) {
                    if (obf) ((u16*)C)[(size_t)r * N + c] = f2bf(acc[mi][ni][j]);
                    else     ((float*)C)[(size_t)r * N + c] = acc[mi][ni][j];
                }
            }
}

// ---------------- q prep: bf16 in [S][NH*192] -> bf16 [NH][S][192], RoPE + scale ----------------
__global__ void prep_q(const u16* __restrict__ q, const float* __restrict__ cosb,
                       const float* __restrict__ sinb, u16* __restrict__ qf) {
    int s = blockIdx.x;
    int d = threadIdx.x; // 192 threads
    float sm = SM_SCALE_C;
    for (int h = 0; h < NHEAD; ++h) {
        const u16* qp = q + (size_t)s * (NHEAD * HEAD_D) + h * HEAD_D;
        float val;
        if (d < NOPE_D) {
            val = bf2f(qp[d]);
        } else {
            int r = d - NOPE_D;
            float x = bf2f(qp[d]);
            float rot = (r < 32) ? -bf2f(qp[NOPE_D + r + 32]) : bf2f(qp[NOPE_D + r - 32]);
            val = x * cosb[s * ROPE_D + r] + rot * sinb[s * ROPE_D + r];
        }
        qf[((size_t)h * S_LEN + s) * HEAD_D + d] = f2bf(val * sm);
    }
}

// ---------------- kv prep: kvb bf16 [S][NH*256], lkv bf16 [S][576] ----------------
// -> k bf16 [NH][S][192], v^T bf16 [NH][128][S]
__global__ void prep_kv(const u16* __restrict__ kvb, const u16* __restrict__ lkv,
                        const float* __restrict__ cosb, const float* __restrict__ sinb,
                        u16* __restrict__ kf, u16* __restrict__ vt) {
    int s = blockIdx.x;
    int d = threadIdx.x; // 192 threads
    u16 kpe = 0;
    if (d >= NOPE_D) {
        int r = d - NOPE_D;
        const u16* kp = lkv + (size_t)s * (KVLORA + ROPE_D) + KVLORA;
        float x = bf2f(kp[r]);
        float rot = (r < 32) ? -bf2f(kp[r + 32]) : bf2f(kp[r - 32]);
        kpe = f2bf(x * cosb[s * ROPE_D + r] + rot * sinb[s * ROPE_D + r]);
    }
    for (int h = 0; h < NHEAD; ++h) {
        const u16* kvp = kvb + (size_t)s * (NHEAD * 256) + h * 256;
        kf[((size_t)h * S_LEN + s) * HEAD_D + d] = (d < NOPE_D) ? kvp[d] : kpe;
        if (d < V_D)
            vt[((size_t)(h * V_D + d)) * S_LEN + s] = kvp[NOPE_D + d];
    }
}

// ---------------- causal flash attention ----------------
// qf/kf: bf16 [NH][S][192] (q pre-scaled); vt: bf16 [NH][128][S]; attn: bf16 [S][NH*128]
__global__ __launch_bounds__(256)
void flash_attn(const u16* __restrict__ qf, const u16* __restrict__ kf,
                const u16* __restrict__ vt, u16* __restrict__ attn) {
    __shared__ u16 Pb[4][16][72];
    const int tid = threadIdx.x, lane = tid & 63, wv = tid >> 6;
    const int b = blockIdx.x;
    const int head = ((b & 7) << 1) | ((b >> 3) & 1);  // 2 heads per XCD (assuming xcd = blk%8)
    const int qt = 31 - (b >> 4);                      // longest blocks dispatch first
    const int q0 = qt * 64 + wv * 16;
    const int lr = lane & 15, lk = lane >> 4;

    const u16* kh_base = kf + (size_t)head * S_LEN * HEAD_D;
    const u16* vh_base = vt + (size_t)head * V_D * S_LEN;

    bf16x8 qfrag[6];
    #pragma unroll
    for (int kk = 0; kk < 6; ++kk)
        qfrag[kk] = *(const bf16x8*)&qf[((size_t)head * S_LEN + q0 + lr) * HEAD_D + kk * 32 + lk * 8];

    f32x4 o[8] = {};
    float m[4], l[4];
    #pragma unroll
    for (int j = 0; j < 4; ++j) { m[j] = -3.0e38f; l[j] = 0.f; }

    for (int kv0 = 0; kv0 <= q0 + 15; kv0 += 64) {
        f32x4 s[4] = {};
        #pragma unroll
        for (int kk = 0; kk < 6; ++kk) {
            bf16x8 kb[4];
            #pragma unroll
            for (int sub = 0; sub < 4; ++sub)
                kb[sub] = *(const bf16x8*)&kh_base[(size_t)(kv0 + sub * 16 + lr) * HEAD_D + kk * 32 + lk * 8];
            #pragma unroll
            for (int sub = 0; sub < 4; ++sub)
                s[sub] = __builtin_amdgcn_mfma_f32_16x16x32_bf16(qfrag[kk], kb[sub], s[sub], 0, 0, 0);
        }
        if (kv0 + 63 > q0) {
            #pragma unroll
            for (int j = 0; j < 4; ++j) {
                int row = q0 + lk * 4 + j;
                #pragma unroll
                for (int sub = 0; sub < 4; ++sub)
                    if (kv0 + sub * 16 + lr > row) s[sub][j] = -3.0e38f;
            }
        }
        float sc[4];
        #pragma unroll
        for (int j = 0; j < 4; ++j) {
            float tm = fmaxf(fmaxf(s[0][j], s[1][j]), fmaxf(s[2][j], s[3][j]));
            #pragma unroll
            for (int off = 1; off < 16; off <<= 1) tm = fmaxf(tm, __shfl_xor(tm, off, 64));
            float mn = fmaxf(m[j], tm);
            float scl = exp2f((m[j] - mn) * LOG2E);
            float psum = 0.f;
            #pragma unroll
            for (int sub = 0; sub < 4; ++sub) {
                float pv = exp2f((s[sub][j] - mn) * LOG2E);
                s[sub][j] = pv;
                psum += pv;
            }
            #pragma unroll
            for (int off = 1; off < 16; off <<= 1) psum += __shfl_xor(psum, off, 64);
            l[j] = l[j] * scl + psum;
            m[j] = mn;
            sc[j] = scl;
        }
        #pragma unroll
        for (int vd = 0; vd < 8; ++vd)
            #pragma unroll
            for (int j = 0; j < 4; ++j) o[vd][j] *= sc[j];
        // transpose P into A-fragment layout via per-wave LDS
        #pragma unroll
        for (int j = 0; j < 4; ++j)
            #pragma unroll
            for (int sub = 0; sub < 4; ++sub)
                Pb[wv][lk * 4 + j][sub * 16 + lr] = f2bf(s[sub][j]);
        asm volatile("s_waitcnt lgkmcnt(0)" ::: "memory");
        __builtin_amdgcn_sched_barrier(0);
        bf16x8 pa0 = *(const bf16x8*)&Pb[wv][lr][lk * 8];
        bf16x8 pa1 = *(const bf16x8*)&Pb[wv][lr][32 + lk * 8];
        #pragma unroll
        for (int vd = 0; vd < 8; ++vd) {
            bf16x8 vb0 = *(const bf16x8*)&vh_base[(size_t)(vd * 16 + lr) * S_LEN + kv0 + lk * 8];
            bf16x8 vb1 = *(const bf16x8*)&vh_base[(size_t)(vd * 16 + lr) * S_LEN + kv0 + 32 + lk * 8];
            o[vd] = __builtin_amdgcn_mfma_f32_16x16x32_bf16(pa0, vb0, o[vd], 0, 0, 0);
            o[vd] = __builtin_amdgcn_mfma_f32_16x16x32_bf16(pa1, vb1, o[vd], 0, 0, 0);
        }
    }

    float inv[4];
    #pragma unroll
    for (int j = 0; j < 4; ++j) inv[j] = 1.0f / l[j];
    #pragma unroll
    for (int vd = 0; vd < 8; ++vd)
        #pragma unroll
        for (int j = 0; j < 4; ++j) {
            int row = q0 + lk * 4 + j;
            attn[(size_t)row * (NHEAD * V_D) + head * V_D + vd * 16 + lr] = f2bf(o[vd][j] * inv[j]);
        }
}

extern "C" void kernel_launch(void* const* d_in, const int* in_sizes, int n_in,
                              void* d_out, int out_size, void* d_ws, size_t ws_size,
                              hipStream_t stream) {
    const float* hs    = (const float*)d_in[0];
    const float* wq_a  = (const float*)d_in[1];
    const float* sq_a  = (const float*)d_in[2];
    const float* wq_b  = (const float*)d_in[3];
    const float* sq_b  = (const float*)d_in[4];
    const float* wkv_a = (const float*)d_in[5];
    const float* skv_a = (const float*)d_in[6];
    const float* wkv_b = (const float*)d_in[7];
    const float* skv_b = (const float*)d_in[8];
    const float* wo    = (const float*)d_in[9];
    const float* so    = (const float*)d_in[10];
    const float* q_ln  = (const float*)d_in[11];
    const float* kv_ln = (const float*)d_in[12];
    const float* cosb  = (const float*)d_in[13];
    const float* sinb  = (const float*)d_in[14];
    float* out = (float*)d_out;

    char* ws = (char*)d_ws;
    size_t off = 0;
    auto alloc = [&](size_t bytes) -> void* {
        void* p = ws + off; off += (bytes + 255) & ~(size_t)255; return p;
    };
    u16* hs_bf  = (u16*)alloc((size_t)S_LEN * HIDDEN * 2);
    u16* lq     = (u16*)alloc((size_t)S_LEN * QLORA * 2);
    u16* lqn    = (u16*)alloc((size_t)S_LEN * QLORA * 2);
    u16* qh     = (u16*)alloc((size_t)S_LEN * NHEAD * HEAD_D * 2);
    u16* q_full = (u16*)alloc((size_t)S_LEN * NHEAD * HEAD_D * 2);
    u16* lkv    = (u16*)alloc((size_t)S_LEN * (KVLORA + ROPE_D) * 2);
    u16* kvn    = (u16*)alloc((size_t)S_LEN * KVLORA * 2);
    u16* kvb    = (u16*)alloc((size_t)S_LEN * NHEAD * 256 * 2);
    u16* k_full = (u16*)alloc((size_t)S_LEN * NHEAD * HEAD_D * 2);
    u16* vt     = (u16*)alloc((size_t)NHEAD * V_D * S_LEN * 2);
    u16* attn   = (u16*)alloc((size_t)S_LEN * NHEAD * V_D * 2);
    // pre-dequantized bf16 weights (rows padded to 128-multiples; pad rows never stored)
    u16* wqa_bf  = (u16*)alloc((size_t)QLORA * HIDDEN * 2);
    u16* wqb_bf  = (u16*)alloc((size_t)(NHEAD * HEAD_D) * QLORA * 2);
    u16* wkva_bf = (u16*)alloc((size_t)640 * HIDDEN * 2);
    u16* wkvb_bf = (u16*)alloc((size_t)(NHEAD * 256) * KVLORA * 2);
    u16* wo_bf   = (u16*)alloc((size_t)HIDDEN * (NHEAD * V_D) * 2);

    cvt_f32_bf16<<<(S_LEN * HIDDEN / 4 + 255) / 256, 256, 0, stream>>>(hs, hs_bf, S_LEN * HIDDEN);

    dequant_w<<<dim3(HIDDEN / 512, QLORA), 64, 0, stream>>>(wq_a, sq_a, wqa_bf, QLORA, HIDDEN, 16);
    dequant_w<<<dim3(QLORA / 512, NHEAD * HEAD_D), 64, 0, stream>>>(wq_b, sq_b, wqb_bf, NHEAD * HEAD_D, QLORA, 12);
    dequant_w<<<dim3(HIDDEN / 512, KVLORA + ROPE_D), 64, 0, stream>>>(wkv_a, skv_a, wkva_bf, KVLORA + ROPE_D, HIDDEN, 16);
    dequant_w<<<dim3(KVLORA / 512, NHEAD * 256), 64, 0, stream>>>(wkv_b, skv_b, wkvb_bf, NHEAD * 256, KVLORA, 4);
    dequant_w<<<dim3((NHEAD * V_D) / 512, HIDDEN), 64, 0, stream>>>(wo, so, wo_bf, HIDDEN, NHEAD * V_D, 16);

    // lq = hs @ wq_a^T   [2048 x 1536]
    gemm_bf16<<<dim3(QLORA / 128, S_LEN / 128), 256, 0, stream>>>(hs_bf, wqa_bf, lq,
        S_LEN, QLORA, HIDDEN, 1);
    rmsnorm_k<<<S_LEN, 256, 0, stream>>>(lq, q_ln, lqn, QLORA, QLORA, QLORA);
    // q = rms(lq) @ wq_b^T  [2048 x 3072]
    gemm_bf16<<<dim3(NHEAD * HEAD_D / 128, S_LEN / 128), 256, 0, stream>>>(lqn, wqb_bf, qh,
        S_LEN, NHEAD * HEAD_D, QLORA, 1);
    // lkv = hs @ wkv_a^T  [2048 x 576]
    gemm_bf16<<<dim3(5, S_LEN / 128), 256, 0, stream>>>(hs_bf, wkva_bf, lkv,
        S_LEN, KVLORA + ROPE_D, HIDDEN, 1);
    rmsnorm_k<<<S_LEN, 256, 0, stream>>>(lkv, kv_ln, kvn, KVLORA, KVLORA + ROPE_D, KVLORA);
    // kvb = kv_nope @ wkv_b^T  [2048 x 4096]
    gemm_bf16<<<dim3(NHEAD * 256 / 128, S_LEN / 128), 256, 0, stream>>>(kvn, wkvb_bf, kvb,
        S_LEN, NHEAD * 256, KVLORA, 1);

    prep_q<<<S_LEN, 192, 0, stream>>>(qh, cosb, sinb, q_full);
    prep_kv<<<S_LEN, 192, 0, stream>>>(kvb, lkv, cosb, sinb, k_full, vt);

    flash_attn<<<512, 256, 0, stream>>>(q_full, k_full, vt, attn);

    // out = attn @ wo^T  [2048 x 2048]
    gemm_bf16<<<dim3(HIDDEN / 128, S_LEN / 128), 256, 0, stream>>>(attn, wo_bf, out,
        S_LEN, HIDDEN, NHEAD * V_D, 0);
}

// Round 3
// 390.118 us; speedup vs baseline: 1.7822x; 1.2206x over previous
//
#include <hip/hip_runtime.h>

typedef unsigned short u16;
typedef unsigned int u32;
typedef __attribute__((ext_vector_type(8))) short bf16x8;
typedef __attribute__((ext_vector_type(4))) float f32x4;
typedef __attribute__((ext_vector_type(16))) float f32x16;
typedef __attribute__((ext_vector_type(4))) unsigned short u16x4;

#define S_LEN 2048
#define HIDDEN 2048
#define NHEAD 16
#define QLORA 1536
#define KVLORA 512
#define NOPE_D 128
#define ROPE_D 64
#define V_D 128
#define HEAD_D 192
#define LOG2E 1.442695041f

// SOFTMAX_SCALE = 192^-0.5 * mscale^2, mscale = 0.1*ln(40)+1
__device__ __constant__ float SM_SCALE_C = (float)(0.07216878364870323 *
    ((0.1 * 3.6888794541139363 + 1.0) * (0.1 * 3.6888794541139363 + 1.0)));

__device__ inline u16 f2bf(float f) {
    union { float f; unsigned int u; } v; v.f = f;
    unsigned int r = v.u + 0x7FFFu + ((v.u >> 16) & 1u);
    return (u16)(r >> 16);
}
__device__ inline float bf2f(u16 b) {
    union { unsigned int u; float f; } v; v.u = ((unsigned int)b) << 16;
    return v.f;
}
__device__ inline void gload_lds16(const u16* g, u16* l) {
    __builtin_amdgcn_global_load_lds(
        (const __attribute__((address_space(1))) void*)g,
        (__attribute__((address_space(3))) void*)l, 16, 0, 0);
}

// ---------------- f32 -> bf16 convert ----------------
__global__ void cvt_f32_bf16(const float* __restrict__ in, u16* __restrict__ out, int n) {
    int i = (blockIdx.x * blockDim.x + threadIdx.x) * 4;
    if (i >= n) return;
    f32x4 v = *(const f32x4*)(in + i);
    u16x4 o;
    o[0] = f2bf(v[0]); o[1] = f2bf(v[1]); o[2] = f2bf(v[2]); o[3] = f2bf(v[3]);
    *(u16x4*)(out + i) = o;
}

// ---------------- weight dequant: f32 [N,K] * blockscale -> bf16 [N,K] ----------------
__global__ __launch_bounds__(64)
void dequant_w(const float* __restrict__ W, const float* __restrict__ Sc,
               u16* __restrict__ out, int N, int K, int sc_cols) {
    int k = (blockIdx.x * 64 + threadIdx.x) * 8;
    int n = blockIdx.y;
    if (k >= K) return;
    float sc = Sc[(n >> 7) * sc_cols + (k >> 7)];
    f32x4 v0 = *(const f32x4*)(W + (size_t)n * K + k);
    f32x4 v1 = *(const f32x4*)(W + (size_t)n * K + k + 4);
    bf16x8 o;
    #pragma unroll
    for (int i = 0; i < 4; ++i) {
        o[i]     = (short)f2bf(v0[i] * sc);
        o[i + 4] = (short)f2bf(v1[i] * sc);
    }
    *(bf16x8*)(out + (size_t)n * K + k) = o;
}

// ---------------- rmsnorm: bf16 in (strided), bf16 out ----------------
__global__ __launch_bounds__(256)
void rmsnorm_k(const u16* __restrict__ in, const float* __restrict__ w,
               u16* __restrict__ out, int D, int istride, int ostride) {
    int row = blockIdx.x;
    const u16* x = in + (size_t)row * istride;
    float ss = 0.f;
    for (int d = threadIdx.x; d < D; d += 256) { float v = bf2f(x[d]); ss += v * v; }
    #pragma unroll
    for (int off = 1; off < 64; off <<= 1) ss += __shfl_xor(ss, off, 64);
    __shared__ float red[4];
    if ((threadIdx.x & 63) == 0) red[threadIdx.x >> 6] = ss;
    __syncthreads();
    float tot = red[0] + red[1] + red[2] + red[3];
    float rs = rsqrtf(tot / (float)D + 1e-6f);
    for (int d = threadIdx.x; d < D; d += 256)
        out[(size_t)row * ostride + d] = f2bf(bf2f(x[d]) * rs * w[d]);
}

// ---------------- bf16 GEMM (m97 structure): C[M,N] = A[M,K] @ W[N,K]^T ----------------
__global__ __launch_bounds__(256)
void gemm_bf16(const u16* __restrict__ A, const u16* __restrict__ W,
               void* __restrict__ C, int M, int N, int K, int obf) {
    __shared__ u16 As[128 * 64];
    __shared__ u16 Ws[128 * 64];
    const int tid = threadIdx.x;
    const int lane = tid & 63;
    const int wv = tid >> 6;
    const int wm = wv >> 1, wn = wv & 1;
    const int bm = blockIdx.y * 128, bn = blockIdx.x * 128;
    const int lr = lane & 15, lk = lane >> 4;
    const int srow = lane >> 3;
    const int schunk = lane & 7;

    f32x4 acc[4][4] = {};

    for (int k0 = 0; k0 < K; k0 += 64) {
        __syncthreads();
        #pragma unroll
        for (int i = 0; i < 4; ++i) {
            int t = (wv * 4 + i) * 8 + srow;
            int cs = (schunk ^ (t & 7)) << 3;
            gload_lds16(A + (size_t)(bm + t) * K + k0 + cs, &As[(wv * 4 + i) * 512]);
            gload_lds16(W + (size_t)(bn + t) * K + k0 + cs, &Ws[(wv * 4 + i) * 512]);
        }
        __syncthreads();
        #pragma unroll
        for (int kh = 0; kh < 2; ++kh) {
            bf16x8 af[4], bfr[4];
            #pragma unroll
            for (int mi = 0; mi < 4; ++mi) {
                int r = wm * 64 + mi * 16 + lr;
                af[mi] = *(const bf16x8*)&As[r * 64 + (((kh * 4 + lk) ^ (lr & 7)) << 3)];
            }
            #pragma unroll
            for (int ni = 0; ni < 4; ++ni) {
                int r = wn * 64 + ni * 16 + lr;
                bfr[ni] = *(const bf16x8*)&Ws[r * 64 + (((kh * 4 + lk) ^ (lr & 7)) << 3)];
            }
            #pragma unroll
            for (int mi = 0; mi < 4; ++mi)
                #pragma unroll
                for (int ni = 0; ni < 4; ++ni)
                    acc[mi][ni] = __builtin_amdgcn_mfma_f32_16x16x32_bf16(af[mi], bfr[ni], acc[mi][ni], 0, 0, 0);
        }
    }

    #pragma unroll
    for (int mi = 0; mi < 4; ++mi)
        #pragma unroll
        for (int ni = 0; ni < 4; ++ni)
            #pragma unroll
            for (int j = 0; j < 4; ++j) {
                int r = bm + wm * 64 + mi * 16 + lk * 4 + j;
                int c = bn + wn * 64 + ni * 16 + lr;
                if (c < N) {
                    if (obf) ((u16*)C)[(size_t)r * N + c] = f2bf(acc[mi][ni][j]);
                    else     ((float*)C)[(size_t)r * N + c] = acc[mi][ni][j];
                }
            }
}

// ---------------- q prep ----------------
__global__ void prep_q(const u16* __restrict__ q, const float* __restrict__ cosb,
                       const float* __restrict__ sinb, u16* __restrict__ qf) {
    int s = blockIdx.x;
    int d = threadIdx.x; // 192 threads
    float sm = SM_SCALE_C;
    for (int h = 0; h < NHEAD; ++h) {
        const u16* qp = q + (size_t)s * (NHEAD * HEAD_D) + h * HEAD_D;
        float val;
        if (d < NOPE_D) {
            val = bf2f(qp[d]);
        } else {
            int r = d - NOPE_D;
            float x = bf2f(qp[d]);
            float rot = (r < 32) ? -bf2f(qp[NOPE_D + r + 32]) : bf2f(qp[NOPE_D + r - 32]);
            val = x * cosb[s * ROPE_D + r] + rot * sinb[s * ROPE_D + r];
        }
        qf[((size_t)h * S_LEN + s) * HEAD_D + d] = f2bf(val * sm);
    }
}

// ---------------- kv prep ----------------
__global__ void prep_kv(const u16* __restrict__ kvb, const u16* __restrict__ lkv,
                        const float* __restrict__ cosb, const float* __restrict__ sinb,
                        u16* __restrict__ kf, u16* __restrict__ vt) {
    int s = blockIdx.x;
    int d = threadIdx.x; // 192 threads
    u16 kpe = 0;
    if (d >= NOPE_D) {
        int r = d - NOPE_D;
        const u16* kp = lkv + (size_t)s * (KVLORA + ROPE_D) + KVLORA;
        float x = bf2f(kp[r]);
        float rot = (r < 32) ? -bf2f(kp[r + 32]) : bf2f(kp[r - 32]);
        kpe = f2bf(x * cosb[s * ROPE_D + r] + rot * sinb[s * ROPE_D + r]);
    }
    for (int h = 0; h < NHEAD; ++h) {
        const u16* kvp = kvb + (size_t)s * (NHEAD * 256) + h * 256;
        kf[((size_t)h * S_LEN + s) * HEAD_D + d] = (d < NOPE_D) ? kvp[d] : kpe;
        if (d < V_D)
            vt[((size_t)(h * V_D + d)) * S_LEN + s] = kvp[NOPE_D + d];
    }
}

// ---------------- causal flash attention v2: swapped operands, all lane-local in q ----
// qf/kf: bf16 [NH][S][192] (q pre-scaled); vt: bf16 [NH][128][S]; attn: bf16 [S][NH*128]
// Grid: 512 blocks x 256 thr. block b: q-tile t = 63-(b>>3) (32 rows), head pair (b&7).
// wave wv: head = 2*(b&7)+(wv>>1), kv-half = wv&1. Two kv-halves merged via LDS.
__global__ __launch_bounds__(256, 2)
void flash_attn2(const u16* __restrict__ qf, const u16* __restrict__ kf,
                 const u16* __restrict__ vt, u16* __restrict__ attn) {
    __shared__ float OB[2][128][32];   // [pair][dv][q] partial O of kv-half B
    __shared__ float MB[2][2][32];     // [pair][{m,l}][q]

    const int tid = threadIdx.x, lane = tid & 63, wv = tid >> 6;
    const int b = blockIdx.x;
    const int t = 63 - (b >> 3);             // q-tile 0..63
    const int pr = wv >> 1;                  // pair index in block (which head)
    const int half = wv & 1;                 // kv-half
    const int h = ((b & 7) << 1) | pr;
    const int q0 = t * 32;
    const int lq = lane & 31;
    const int hi = lane >> 5;                // 0/1
    const int hi8 = hi * 8;

    const int n = t + 1;
    const int mid = (n + 1) >> 1;
    const int s_lo = half ? mid : 0;
    const int s_hi = half ? n : mid;

    // persistent Q B-fragments: B[k=d][col=q]: lane holds col=lq, d = kk*16 + hi8 + j
    bf16x8 qfrag[12];
    {
        const u16* qb = qf + ((size_t)h * S_LEN + q0 + lq) * HEAD_D + hi8;
        #pragma unroll
        for (int kk = 0; kk < 12; ++kk)
            qfrag[kk] = *(const bf16x8*)(qb + kk * 16);
    }

    const u16* kb0 = kf + ((size_t)h * S_LEN + lq) * HEAD_D + hi8;
    const u16* vb0 = vt + ((size_t)h * V_D + lq) * S_LEN + hi8;

    f32x16 oa[4] = {};
    float mrun = -3.0e38f, lrun = 0.f;

    for (int sub = s_lo; sub < s_hi; ++sub) {
        const int kv0 = sub * 32;
        // ---- QK^T (swapped): S^T[kv,q], A=K rows=kv, B=Q cols=q ----
        f32x16 s0 = {}, s1 = {};
        const u16* kp = kb0 + (size_t)kv0 * HEAD_D;
        #pragma unroll
        for (int kk = 0; kk < 12; kk += 2) {
            bf16x8 ka0 = *(const bf16x8*)(kp + kk * 16);
            bf16x8 ka1 = *(const bf16x8*)(kp + kk * 16 + 16);
            s0 = __builtin_amdgcn_mfma_f32_32x32x16_bf16(ka0, qfrag[kk], s0, 0, 0, 0);
            s1 = __builtin_amdgcn_mfma_f32_32x32x16_bf16(ka1, qfrag[kk + 1], s1, 0, 0, 0);
        }
        f32x16 sv = s0 + s1;
        // causal mask (only the diagonal subtile needs it; kv0 == q0 there)
        if (sub == t) {
            #pragma unroll
            for (int r = 0; r < 16; ++r) {
                int krow = (r & 3) + 8 * (r >> 2) + 4 * hi;
                if (krow > lq) sv[r] = -3.0e38f;
            }
        }
        // ---- row max (lane-local in q) ----
        float tm = sv[0];
        #pragma unroll
        for (int r = 1; r < 16; ++r) tm = fmaxf(tm, sv[r]);
        tm = fmaxf(tm, __shfl_xor(tm, 32, 64));
        // defer-max: only rescale when the max moved meaningfully
        if (!__all(tm - mrun <= 8.f)) {
            float mn = fmaxf(mrun, tm);
            float scl = exp2f((mrun - mn) * LOG2E);
            mrun = mn;
            lrun *= scl;
            #pragma unroll
            for (int bb = 0; bb < 4; ++bb)
                #pragma unroll
                for (int r = 0; r < 16; ++r) oa[bb][r] *= scl;
        }
        // ---- P = exp(s - m), row sum ----
        float p[16];
        float psum = 0.f;
        #pragma unroll
        for (int r = 0; r < 16; ++r) {
            p[r] = exp2f((sv[r] - mrun) * LOG2E);
            psum += p[r];
        }
        psum += __shfl_xor(psum, 32, 64);
        lrun += psum;
        // ---- pack P to bf16 words, redistribute across lane halves ----
        u32 pw[8], sw[8];
        #pragma unroll
        for (int i = 0; i < 8; ++i)
            pw[i] = (u32)f2bf(p[2 * i]) | ((u32)f2bf(p[2 * i + 1]) << 16);
        #pragma unroll
        for (int i = 0; i < 8; ++i)
            sw[i] = (u32)__shfl_xor((int)pw[i], 32, 64);
        union { u32 w[4]; bf16x8 v; } bf0, bf1;
        bf0.w[0] = hi ? sw[2] : pw[0];
        bf0.w[1] = hi ? sw[3] : pw[1];
        bf0.w[2] = hi ? pw[2] : sw[0];
        bf0.w[3] = hi ? pw[3] : sw[1];
        bf1.w[0] = hi ? sw[6] : pw[4];
        bf1.w[1] = hi ? sw[7] : pw[5];
        bf1.w[2] = hi ? pw[6] : sw[4];
        bf1.w[3] = hi ? pw[7] : sw[5];
        // ---- PV: O^T = mfma(A=V^T rows=dv, B=P^T cols=q) ----
        #pragma unroll
        for (int bb = 0; bb < 4; ++bb) {
            const u16* vp = vb0 + (size_t)(bb * 32) * S_LEN + kv0;
            bf16x8 va0 = *(const bf16x8*)(vp);
            bf16x8 va1 = *(const bf16x8*)(vp + 16);
            oa[bb] = __builtin_amdgcn_mfma_f32_32x32x16_bf16(va0, bf0.v, oa[bb], 0, 0, 0);
            oa[bb] = __builtin_amdgcn_mfma_f32_32x32x16_bf16(va1, bf1.v, oa[bb], 0, 0, 0);
        }
    }

    // ---- merge the two kv-halves ----
    if (half) {
        #pragma unroll
        for (int bb = 0; bb < 4; ++bb)
            #pragma unroll
            for (int r = 0; r < 16; ++r) {
                int dv = bb * 32 + (r & 3) + 8 * (r >> 2) + 4 * hi;
                OB[pr][dv][lq] = oa[bb][r];
            }
        if (lane < 32) {
            MB[pr][0][lane] = mrun;
            MB[pr][1][lane] = lrun;
        }
    }
    __syncthreads();
    if (!half) {
        float mB = MB[pr][0][lq];
        float lB = MB[pr][1][lq];
        float M = fmaxf(mrun, mB);
        float eA = exp2f((mrun - M) * LOG2E);
        float eB = exp2f((mB - M) * LOG2E);
        float L = lrun * eA + lB * eB;
        float inv = 1.0f / L;
        u16* ob = attn + (size_t)(q0 + lq) * (NHEAD * V_D) + h * V_D;
        #pragma unroll
        for (int bb = 0; bb < 4; ++bb)
            #pragma unroll
            for (int rq = 0; rq < 4; ++rq) {
                u16x4 pk;
                #pragma unroll
                for (int rb = 0; rb < 4; ++rb) {
                    int r = rq * 4 + rb;
                    int dv = bb * 32 + rb + 8 * rq + 4 * hi;
                    float o = (oa[bb][r] * eA + OB[pr][dv][lq] * eB) * inv;
                    pk[rb] = f2bf(o);
                }
                *(u16x4*)(ob + bb * 32 + 8 * rq + 4 * hi) = pk;
            }
    }
}

extern "C" void kernel_launch(void* const* d_in, const int* in_sizes, int n_in,
                              void* d_out, int out_size, void* d_ws, size_t ws_size,
                              hipStream_t stream) {
    const float* hs    = (const float*)d_in[0];
    const float* wq_a  = (const float*)d_in[1];
    const float* sq_a  = (const float*)d_in[2];
    const float* wq_b  = (const float*)d_in[3];
    const float* sq_b  = (const float*)d_in[4];
    const float* wkv_a = (const float*)d_in[5];
    const float* skv_a = (const float*)d_in[6];
    const float* wkv_b = (const float*)d_in[7];
    const float* skv_b = (const float*)d_in[8];
    const float* wo    = (const float*)d_in[9];
    const float* so    = (const float*)d_in[10];
    const float* q_ln  = (const float*)d_in[11];
    const float* kv_ln = (const float*)d_in[12];
    const float* cosb  = (const float*)d_in[13];
    const float* sinb  = (const float*)d_in[14];
    float* out = (float*)d_out;

    char* ws = (char*)d_ws;
    size_t off = 0;
    auto alloc = [&](size_t bytes) -> void* {
        void* p = ws + off; off += (bytes + 255) & ~(size_t)255; return p;
    };
    u16* hs_bf  = (u16*)alloc((size_t)S_LEN * HIDDEN * 2);
    u16* lq     = (u16*)alloc((size_t)S_LEN * QLORA * 2);
    u16* lqn    = (u16*)alloc((size_t)S_LEN * QLORA * 2);
    u16* qh     = (u16*)alloc((size_t)S_LEN * NHEAD * HEAD_D * 2);
    u16* q_full = (u16*)alloc((size_t)S_LEN * NHEAD * HEAD_D * 2);
    u16* lkv    = (u16*)alloc((size_t)S_LEN * (KVLORA + ROPE_D) * 2);
    u16* kvn    = (u16*)alloc((size_t)S_LEN * KVLORA * 2);
    u16* kvb    = (u16*)alloc((size_t)S_LEN * NHEAD * 256 * 2);
    u16* k_full = (u16*)alloc((size_t)S_LEN * NHEAD * HEAD_D * 2);
    u16* vt     = (u16*)alloc((size_t)NHEAD * V_D * S_LEN * 2);
    u16* attn   = (u16*)alloc((size_t)S_LEN * NHEAD * V_D * 2);
    u16* wqa_bf  = (u16*)alloc((size_t)QLORA * HIDDEN * 2);
    u16* wqb_bf  = (u16*)alloc((size_t)(NHEAD * HEAD_D) * QLORA * 2);
    u16* wkva_bf = (u16*)alloc((size_t)640 * HIDDEN * 2);
    u16* wkvb_bf = (u16*)alloc((size_t)(NHEAD * 256) * KVLORA * 2);
    u16* wo_bf   = (u16*)alloc((size_t)HIDDEN * (NHEAD * V_D) * 2);

    cvt_f32_bf16<<<(S_LEN * HIDDEN / 4 + 255) / 256, 256, 0, stream>>>(hs, hs_bf, S_LEN * HIDDEN);

    dequant_w<<<dim3(HIDDEN / 512, QLORA), 64, 0, stream>>>(wq_a, sq_a, wqa_bf, QLORA, HIDDEN, 16);
    dequant_w<<<dim3(QLORA / 512, NHEAD * HEAD_D), 64, 0, stream>>>(wq_b, sq_b, wqb_bf, NHEAD * HEAD_D, QLORA, 12);
    dequant_w<<<dim3(HIDDEN / 512, KVLORA + ROPE_D), 64, 0, stream>>>(wkv_a, skv_a, wkva_bf, KVLORA + ROPE_D, HIDDEN, 16);
    dequant_w<<<dim3(KVLORA / 512, NHEAD * 256), 64, 0, stream>>>(wkv_b, skv_b, wkvb_bf, NHEAD * 256, KVLORA, 4);
    dequant_w<<<dim3((NHEAD * V_D) / 512, HIDDEN), 64, 0, stream>>>(wo, so, wo_bf, HIDDEN, NHEAD * V_D, 16);

    gemm_bf16<<<dim3(QLORA / 128, S_LEN / 128), 256, 0, stream>>>(hs_bf, wqa_bf, lq,
        S_LEN, QLORA, HIDDEN, 1);
    rmsnorm_k<<<S_LEN, 256, 0, stream>>>(lq, q_ln, lqn, QLORA, QLORA, QLORA);
    gemm_bf16<<<dim3(NHEAD * HEAD_D / 128, S_LEN / 128), 256, 0, stream>>>(lqn, wqb_bf, qh,
        S_LEN, NHEAD * HEAD_D, QLORA, 1);
    gemm_bf16<<<dim3(5, S_LEN / 128), 256, 0, stream>>>(hs_bf, wkva_bf, lkv,
        S_LEN, KVLORA + ROPE_D, HIDDEN, 1);
    rmsnorm_k<<<S_LEN, 256, 0, stream>>>(lkv, kv_ln, kvn, KVLORA, KVLORA + ROPE_D, KVLORA);
    gemm_bf16<<<dim3(NHEAD * 256 / 128, S_LEN / 128), 256, 0, stream>>>(kvn, wkvb_bf, kvb,
        S_LEN, NHEAD * 256, KVLORA, 1);

    prep_q<<<S_LEN, 192, 0, stream>>>(qh, cosb, sinb, q_full);
    prep_kv<<<S_LEN, 192, 0, stream>>>(kvb, lkv, cosb, sinb, k_full, vt);

    flash_attn2<<<512, 256, 0, stream>>>(q_full, k_full, vt, attn);

    gemm_bf16<<<dim3(HIDDEN / 128, S_LEN / 128), 256, 0, stream>>>(attn, wo_bf, out,
        S_LEN, HIDDEN, NHEAD * V_D, 0);
}

// Round 4
// 374.569 us; speedup vs baseline: 1.8561x; 1.0415x over previous
//
#include <hip/hip_runtime.h>

typedef unsigned short u16;
typedef unsigned int u32;
typedef __attribute__((ext_vector_type(8))) short bf16x8;
typedef __attribute__((ext_vector_type(4))) float f32x4;
typedef __attribute__((ext_vector_type(16))) float f32x16;
typedef __attribute__((ext_vector_type(4))) unsigned short u16x4;

#define S_LEN 2048
#define HIDDEN 2048
#define NHEAD 16
#define QLORA 1536
#define KVLORA 512
#define NOPE_D 128
#define ROPE_D 64
#define V_D 128
#define HEAD_D 192
#define LOG2E 1.442695041f

// SOFTMAX_SCALE = 192^-0.5 * mscale^2, mscale = 0.1*ln(40)+1
__device__ __constant__ float SM_SCALE_C = (float)(0.07216878364870323 *
    ((0.1 * 3.6888794541139363 + 1.0) * (0.1 * 3.6888794541139363 + 1.0)));

__device__ inline u16 f2bf(float f) {
    union { float f; unsigned int u; } v; v.f = f;
    unsigned int r = v.u + 0x7FFFu + ((v.u >> 16) & 1u);
    return (u16)(r >> 16);
}
__device__ inline float bf2f(u16 b) {
    union { unsigned int u; float f; } v; v.u = ((unsigned int)b) << 16;
    return v.f;
}
__device__ inline void gload_lds16(const u16* g, u16* l) {
    __builtin_amdgcn_global_load_lds(
        (const __attribute__((address_space(1))) void*)g,
        (__attribute__((address_space(3))) void*)l, 16, 0, 0);
}

// ---------------- f32 -> bf16 convert ----------------
__global__ void cvt_f32_bf16(const float* __restrict__ in, u16* __restrict__ out, int n) {
    int i = (blockIdx.x * blockDim.x + threadIdx.x) * 4;
    if (i >= n) return;
    f32x4 v = *(const f32x4*)(in + i);
    u16x4 o;
    o[0] = f2bf(v[0]); o[1] = f2bf(v[1]); o[2] = f2bf(v[2]); o[3] = f2bf(v[3]);
    *(u16x4*)(out + i) = o;
}

// ---------------- weight dequant: f32 [N,K] * blockscale -> bf16 [N,K] ----------------
__global__ __launch_bounds__(64)
void dequant_w(const float* __restrict__ W, const float* __restrict__ Sc,
               u16* __restrict__ out, int N, int K, int sc_cols) {
    int k = (blockIdx.x * 64 + threadIdx.x) * 8;
    int n = blockIdx.y;
    if (k >= K) return;
    float sc = Sc[(n >> 7) * sc_cols + (k >> 7)];
    f32x4 v0 = *(const f32x4*)(W + (size_t)n * K + k);
    f32x4 v1 = *(const f32x4*)(W + (size_t)n * K + k + 4);
    bf16x8 o;
    #pragma unroll
    for (int i = 0; i < 4; ++i) {
        o[i]     = (short)f2bf(v0[i] * sc);
        o[i + 4] = (short)f2bf(v1[i] * sc);
    }
    *(bf16x8*)(out + (size_t)n * K + k) = o;
}

// ---------------- rmsnorm: bf16 in (strided), bf16 out ----------------
__global__ __launch_bounds__(256)
void rmsnorm_k(const u16* __restrict__ in, const float* __restrict__ w,
               u16* __restrict__ out, int D, int istride, int ostride) {
    int row = blockIdx.x;
    const u16* x = in + (size_t)row * istride;
    float ss = 0.f;
    for (int d = threadIdx.x; d < D; d += 256) { float v = bf2f(x[d]); ss += v * v; }
    #pragma unroll
    for (int off = 1; off < 64; off <<= 1) ss += __shfl_xor(ss, off, 64);
    __shared__ float red[4];
    if ((threadIdx.x & 63) == 0) red[threadIdx.x >> 6] = ss;
    __syncthreads();
    float tot = red[0] + red[1] + red[2] + red[3];
    float rs = rsqrtf(tot / (float)D + 1e-6f);
    for (int d = threadIdx.x; d < D; d += 256)
        out[(size_t)row * ostride + d] = f2bf(bf2f(x[d]) * rs * w[d]);
}

// ---------------- bf16 GEMM (m97 structure): C[M,N] = A[M,K] @ W[N,K]^T ----------------
__global__ __launch_bounds__(256)
void gemm_bf16(const u16* __restrict__ A, const u16* __restrict__ W,
               void* __restrict__ C, int M, int N, int K, int obf) {
    __shared__ u16 As[128 * 64];
    __shared__ u16 Ws[128 * 64];
    const int tid = threadIdx.x;
    const int lane = tid & 63;
    const int wv = tid >> 6;
    const int wm = wv >> 1, wn = wv & 1;
    const int bm = blockIdx.y * 128, bn = blockIdx.x * 128;
    const int lr = lane & 15, lk = lane >> 4;
    const int srow = lane >> 3;
    const int schunk = lane & 7;

    f32x4 acc[4][4] = {};

    for (int k0 = 0; k0 < K; k0 += 64) {
        __syncthreads();
        #pragma unroll
        for (int i = 0; i < 4; ++i) {
            int t = (wv * 4 + i) * 8 + srow;
            int cs = (schunk ^ (t & 7)) << 3;
            gload_lds16(A + (size_t)(bm + t) * K + k0 + cs, &As[(wv * 4 + i) * 512]);
            gload_lds16(W + (size_t)(bn + t) * K + k0 + cs, &Ws[(wv * 4 + i) * 512]);
        }
        __syncthreads();
        #pragma unroll
        for (int kh = 0; kh < 2; ++kh) {
            bf16x8 af[4], bfr[4];
            #pragma unroll
            for (int mi = 0; mi < 4; ++mi) {
                int r = wm * 64 + mi * 16 + lr;
                af[mi] = *(const bf16x8*)&As[r * 64 + (((kh * 4 + lk) ^ (lr & 7)) << 3)];
            }
            #pragma unroll
            for (int ni = 0; ni < 4; ++ni) {
                int r = wn * 64 + ni * 16 + lr;
                bfr[ni] = *(const bf16x8*)&Ws[r * 64 + (((kh * 4 + lk) ^ (lr & 7)) << 3)];
            }
            #pragma unroll
            for (int mi = 0; mi < 4; ++mi)
                #pragma unroll
                for (int ni = 0; ni < 4; ++ni)
                    acc[mi][ni] = __builtin_amdgcn_mfma_f32_16x16x32_bf16(af[mi], bfr[ni], acc[mi][ni], 0, 0, 0);
        }
    }

    #pragma unroll
    for (int mi = 0; mi < 4; ++mi)
        #pragma unroll
        for (int ni = 0; ni < 4; ++ni)
            #pragma unroll
            for (int j = 0; j < 4; ++j) {
                int r = bm + wm * 64 + mi * 16 + lk * 4 + j;
                int c = bn + wn * 64 + ni * 16 + lr;
                if (c < N) {
                    if (obf) ((u16*)C)[(size_t)r * N + c] = f2bf(acc[mi][ni][j]);
                    else     ((float*)C)[(size_t)r * N + c] = acc[mi][ni][j];
                }
            }
}

// ---------------- q prep ----------------
__global__ void prep_q(const u16* __restrict__ q, const float* __restrict__ cosb,
                       const float* __restrict__ sinb, u16* __restrict__ qf) {
    int s = blockIdx.x;
    int d = threadIdx.x; // 192 threads
    float sm = SM_SCALE_C;
    for (int h = 0; h < NHEAD; ++h) {
        const u16* qp = q + (size_t)s * (NHEAD * HEAD_D) + h * HEAD_D;
        float val;
        if (d < NOPE_D) {
            val = bf2f(qp[d]);
        } else {
            int r = d - NOPE_D;
            float x = bf2f(qp[d]);
            float rot = (r < 32) ? -bf2f(qp[NOPE_D + r + 32]) : bf2f(qp[NOPE_D + r - 32]);
            val = x * cosb[s * ROPE_D + r] + rot * sinb[s * ROPE_D + r];
        }
        qf[((size_t)h * S_LEN + s) * HEAD_D + d] = f2bf(val * sm);
    }
}

// ---------------- kv prep ----------------
__global__ void prep_kv(const u16* __restrict__ kvb, const u16* __restrict__ lkv,
                        const float* __restrict__ cosb, const float* __restrict__ sinb,
                        u16* __restrict__ kf, u16* __restrict__ vt) {
    int s = blockIdx.x;
    int d = threadIdx.x; // 192 threads
    u16 kpe = 0;
    if (d >= NOPE_D) {
        int r = d - NOPE_D;
        const u16* kp = lkv + (size_t)s * (KVLORA + ROPE_D) + KVLORA;
        float x = bf2f(kp[r]);
        float rot = (r < 32) ? -bf2f(kp[r + 32]) : bf2f(kp[r - 32]);
        kpe = f2bf(x * cosb[s * ROPE_D + r] + rot * sinb[s * ROPE_D + r]);
    }
    for (int h = 0; h < NHEAD; ++h) {
        const u16* kvp = kvb + (size_t)s * (NHEAD * 256) + h * 256;
        kf[((size_t)h * S_LEN + s) * HEAD_D + d] = (d < NOPE_D) ? kvp[d] : kpe;
        if (d < V_D)
            vt[((size_t)(h * V_D + d)) * S_LEN + s] = kvp[NOPE_D + d];
    }
}

// ---------------- causal flash attention v3: swapped operands + T14 pipeline ----------
// qf/kf: bf16 [NH][S][192] (q pre-scaled); vt: bf16 [NH][128][S]; attn: bf16 [S][NH*128]
// Grid: 512 blocks x 256 thr. block b: q-tile t = 63-(b>>3), head pair (b&7).
// wave wv: head = 2*(b&7)+(wv>>1), kv-half = wv&1. Halves merged via LDS.
// K loads for subtile i+1 issue right after QK^T of i consumes kcur (same regs);
// V loads for i issue before softmax. Both covered by ~500cy of VALU/MFMA.
__global__ __launch_bounds__(256, 2)
void flash_attn2(const u16* __restrict__ qf, const u16* __restrict__ kf,
                 const u16* __restrict__ vt, u16* __restrict__ attn) {
    __shared__ float OB[2][128][32];   // [pair][dv][q] partial O of kv-half B
    __shared__ float MB[2][2][32];     // [pair][{m,l}][q]

    const int tid = threadIdx.x, lane = tid & 63, wv = tid >> 6;
    const int b = blockIdx.x;
    const int t = 63 - (b >> 3);             // q-tile 0..63 (heavy first)
    const int pr = wv >> 1;                  // which head of the pair
    const int half = wv & 1;                 // kv-half
    const int h = ((b & 7) << 1) | pr;
    const int q0 = t * 32;
    const int lq = lane & 31;
    const int hi = lane >> 5;                // 0/1
    const int hi8 = hi * 8;

    const int n = t + 1;
    const int mid = (n + 1) >> 1;
    const int s_lo = half ? mid : 0;
    const int s_hi = half ? n : mid;

    // persistent Q B-fragments
    bf16x8 qfrag[12];
    {
        const u16* qb = qf + ((size_t)h * S_LEN + q0 + lq) * HEAD_D + hi8;
        #pragma unroll
        for (int kk = 0; kk < 12; ++kk)
            qfrag[kk] = *(const bf16x8*)(qb + kk * 16);
    }

    const u16* kb0 = kf + ((size_t)h * S_LEN + lq) * HEAD_D + hi8;
    const u16* vb0 = vt + ((size_t)h * V_D + lq) * S_LEN + hi8;

    f32x16 oa[4] = {};
    float mrun = -3.0e38f, lrun = 0.f;

    // preload K fragments for first subtile
    bf16x8 kcur[12];
    {
        int pk0 = (s_lo < s_hi ? s_lo : (n - 1)) * 32;
        const u16* kp = kb0 + (size_t)pk0 * HEAD_D;
        #pragma unroll
        for (int kk = 0; kk < 12; ++kk)
            kcur[kk] = *(const bf16x8*)(kp + kk * 16);
    }

    for (int sub = s_lo; sub < s_hi; ++sub) {
        const int kv0 = sub * 32;
        // ---- QK^T (swapped): S^T[kv,q] ----
        f32x16 s0 = {}, s1 = {};
        __builtin_amdgcn_s_setprio(1);
        #pragma unroll
        for (int kk = 0; kk < 12; kk += 2) {
            s0 = __builtin_amdgcn_mfma_f32_32x32x16_bf16(kcur[kk], qfrag[kk], s0, 0, 0, 0);
            s1 = __builtin_amdgcn_mfma_f32_32x32x16_bf16(kcur[kk + 1], qfrag[kk + 1], s1, 0, 0, 0);
        }
        __builtin_amdgcn_s_setprio(0);
        // ---- T14: kcur dead -> issue K loads for NEXT subtile now ----
        {
            int nsub = (sub + 1 < s_hi) ? sub + 1 : sub;
            const u16* kp = kb0 + (size_t)(nsub * 32) * HEAD_D;
            #pragma unroll
            for (int kk = 0; kk < 12; ++kk)
                kcur[kk] = *(const bf16x8*)(kp + kk * 16);
        }
        // ---- V loads for CURRENT subtile (consumed after softmax) ----
        bf16x8 va[8];
        #pragma unroll
        for (int bb = 0; bb < 4; ++bb) {
            const u16* vp = vb0 + (size_t)(bb * 32) * S_LEN + kv0;
            va[bb * 2]     = *(const bf16x8*)(vp);
            va[bb * 2 + 1] = *(const bf16x8*)(vp + 16);
        }
        f32x16 sv = s0 + s1;
        // causal mask (diagonal subtile only)
        if (sub == t) {
            #pragma unroll
            for (int r = 0; r < 16; ++r) {
                int krow = (r & 3) + 8 * (r >> 2) + 4 * hi;
                if (krow > lq) sv[r] = -3.0e38f;
            }
        }
        // ---- row max (lane-local in q) ----
        float tm = sv[0];
        #pragma unroll
        for (int r = 1; r < 16; ++r) tm = fmaxf(tm, sv[r]);
        tm = fmaxf(tm, __shfl_xor(tm, 32, 64));
        // defer-max
        if (!__all(tm - mrun <= 8.f)) {
            float mn = fmaxf(mrun, tm);
            float scl = exp2f((mrun - mn) * LOG2E);
            mrun = mn;
            lrun *= scl;
            #pragma unroll
            for (int bb = 0; bb < 4; ++bb)
                #pragma unroll
                for (int r = 0; r < 16; ++r) oa[bb][r] *= scl;
        }
        // ---- P = exp(s - m), row sum ----
        float p[16];
        float psum = 0.f;
        #pragma unroll
        for (int r = 0; r < 16; ++r) {
            p[r] = exp2f((sv[r] - mrun) * LOG2E);
            psum += p[r];
        }
        psum += __shfl_xor(psum, 32, 64);
        lrun += psum;
        // ---- pack P to bf16, redistribute across lane halves ----
        u32 pw[8], sw[8];
        #pragma unroll
        for (int i = 0; i < 8; ++i)
            pw[i] = (u32)f2bf(p[2 * i]) | ((u32)f2bf(p[2 * i + 1]) << 16);
        #pragma unroll
        for (int i = 0; i < 8; ++i)
            sw[i] = (u32)__shfl_xor((int)pw[i], 32, 64);
        union { u32 w[4]; bf16x8 v; } bf0, bf1;
        bf0.w[0] = hi ? sw[2] : pw[0];
        bf0.w[1] = hi ? sw[3] : pw[1];
        bf0.w[2] = hi ? pw[2] : sw[0];
        bf0.w[3] = hi ? pw[3] : sw[1];
        bf1.w[0] = hi ? sw[6] : pw[4];
        bf1.w[1] = hi ? sw[7] : pw[5];
        bf1.w[2] = hi ? pw[6] : sw[4];
        bf1.w[3] = hi ? pw[7] : sw[5];
        // ---- PV: O^T = mfma(A=V^T, B=P^T) ----
        __builtin_amdgcn_s_setprio(1);
        #pragma unroll
        for (int bb = 0; bb < 4; ++bb) {
            oa[bb] = __builtin_amdgcn_mfma_f32_32x32x16_bf16(va[bb * 2],     bf0.v, oa[bb], 0, 0, 0);
            oa[bb] = __builtin_amdgcn_mfma_f32_32x32x16_bf16(va[bb * 2 + 1], bf1.v, oa[bb], 0, 0, 0);
        }
        __builtin_amdgcn_s_setprio(0);
    }

    // ---- merge the two kv-halves ----
    if (half) {
        #pragma unroll
        for (int bb = 0; bb < 4; ++bb)
            #pragma unroll
            for (int r = 0; r < 16; ++r) {
                int dv = bb * 32 + (r & 3) + 8 * (r >> 2) + 4 * hi;
                OB[pr][dv][lq] = oa[bb][r];
            }
        if (lane < 32) {
            MB[pr][0][lane] = mrun;
            MB[pr][1][lane] = lrun;
        }
    }
    __syncthreads();
    if (!half) {
        float mB = MB[pr][0][lq];
        float lB = MB[pr][1][lq];
        float M = fmaxf(mrun, mB);
        float eA = exp2f((mrun - M) * LOG2E);
        float eB = exp2f((mB - M) * LOG2E);
        float L = lrun * eA + lB * eB;
        float inv = 1.0f / L;
        u16* ob = attn + (size_t)(q0 + lq) * (NHEAD * V_D) + h * V_D;
        #pragma unroll
        for (int bb = 0; bb < 4; ++bb)
            #pragma unroll
            for (int rq = 0; rq < 4; ++rq) {
                u16x4 pk;
                #pragma unroll
                for (int rb = 0; rb < 4; ++rb) {
                    int r = rq * 4 + rb;
                    int dv = bb * 32 + rb + 8 * rq + 4 * hi;
                    float o = (oa[bb][r] * eA + OB[pr][dv][lq] * eB) * inv;
                    pk[rb] = f2bf(o);
                }
                *(u16x4*)(ob + bb * 32 + 8 * rq + 4 * hi) = pk;
            }
    }
}

extern "C" void kernel_launch(void* const* d_in, const int* in_sizes, int n_in,
                              void* d_out, int out_size, void* d_ws, size_t ws_size,
                              hipStream_t stream) {
    const float* hs    = (const float*)d_in[0];
    const float* wq_a  = (const float*)d_in[1];
    const float* sq_a  = (const float*)d_in[2];
    const float* wq_b  = (const float*)d_in[3];
    const float* sq_b  = (const float*)d_in[4];
    const float* wkv_a = (const float*)d_in[5];
    const float* skv_a = (const float*)d_in[6];
    const float* wkv_b = (const float*)d_in[7];
    const float* skv_b = (const float*)d_in[8];
    const float* wo    = (const float*)d_in[9];
    const float* so    = (const float*)d_in[10];
    const float* q_ln  = (const float*)d_in[11];
    const float* kv_ln = (const float*)d_in[12];
    const float* cosb  = (const float*)d_in[13];
    const float* sinb  = (const float*)d_in[14];
    float* out = (float*)d_out;

    char* ws = (char*)d_ws;
    size_t off = 0;
    auto alloc = [&](size_t bytes) -> void* {
        void* p = ws + off; off += (bytes + 255) & ~(size_t)255; return p;
    };
    u16* hs_bf  = (u16*)alloc((size_t)S_LEN * HIDDEN * 2);
    u16* lq     = (u16*)alloc((size_t)S_LEN * QLORA * 2);
    u16* lqn    = (u16*)alloc((size_t)S_LEN * QLORA * 2);
    u16* qh     = (u16*)alloc((size_t)S_LEN * NHEAD * HEAD_D * 2);
    u16* q_full = (u16*)alloc((size_t)S_LEN * NHEAD * HEAD_D * 2);
    u16* lkv    = (u16*)alloc((size_t)S_LEN * (KVLORA + ROPE_D) * 2);
    u16* kvn    = (u16*)alloc((size_t)S_LEN * KVLORA * 2);
    u16* kvb    = (u16*)alloc((size_t)S_LEN * NHEAD * 256 * 2);
    u16* k_full = (u16*)alloc((size_t)S_LEN * NHEAD * HEAD_D * 2);
    u16* vt     = (u16*)alloc((size_t)NHEAD * V_D * S_LEN * 2);
    u16* attn   = (u16*)alloc((size_t)S_LEN * NHEAD * V_D * 2);
    u16* wqa_bf  = (u16*)alloc((size_t)QLORA * HIDDEN * 2);
    u16* wqb_bf  = (u16*)alloc((size_t)(NHEAD * HEAD_D) * QLORA * 2);
    u16* wkva_bf = (u16*)alloc((size_t)640 * HIDDEN * 2);
    u16* wkvb_bf = (u16*)alloc((size_t)(NHEAD * 256) * KVLORA * 2);
    u16* wo_bf   = (u16*)alloc((size_t)HIDDEN * (NHEAD * V_D) * 2);

    cvt_f32_bf16<<<(S_LEN * HIDDEN / 4 + 255) / 256, 256, 0, stream>>>(hs, hs_bf, S_LEN * HIDDEN);

    dequant_w<<<dim3(HIDDEN / 512, QLORA), 64, 0, stream>>>(wq_a, sq_a, wqa_bf, QLORA, HIDDEN, 16);
    dequant_w<<<dim3(QLORA / 512, NHEAD * HEAD_D), 64, 0, stream>>>(wq_b, sq_b, wqb_bf, NHEAD * HEAD_D, QLORA, 12);
    dequant_w<<<dim3(HIDDEN / 512, KVLORA + ROPE_D), 64, 0, stream>>>(wkv_a, skv_a, wkva_bf, KVLORA + ROPE_D, HIDDEN, 16);
    dequant_w<<<dim3(KVLORA / 512, NHEAD * 256), 64, 0, stream>>>(wkv_b, skv_b, wkvb_bf, NHEAD * 256, KVLORA, 4);
    dequant_w<<<dim3((NHEAD * V_D) / 512, HIDDEN), 64, 0, stream>>>(wo, so, wo_bf, HIDDEN, NHEAD * V_D, 16);

    gemm_bf16<<<dim3(QLORA / 128, S_LEN / 128), 256, 0, stream>>>(hs_bf, wqa_bf, lq,
        S_LEN, QLORA, HIDDEN, 1);
    rmsnorm_k<<<S_LEN, 256, 0, stream>>>(lq, q_ln, lqn, QLORA, QLORA, QLORA);
    gemm_bf16<<<dim3(NHEAD * HEAD_D / 128, S_LEN / 128), 256, 0, stream>>>(lqn, wqb_bf, qh,
        S_LEN, NHEAD * HEAD_D, QLORA, 1);
    gemm_bf16<<<dim3(5, S_LEN / 128), 256, 0, stream>>>(hs_bf, wkva_bf, lkv,
        S_LEN, KVLORA + ROPE_D, HIDDEN, 1);
    rmsnorm_k<<<S_LEN, 256, 0, stream>>>(lkv, kv_ln, kvn, KVLORA, KVLORA + ROPE_D, KVLORA);
    gemm_bf16<<<dim3(NHEAD * 256 / 128, S_LEN / 128), 256, 0, stream>>>(kvn, wkvb_bf, kvb,
        S_LEN, NHEAD * 256, KVLORA, 1);

    prep_q<<<S_LEN, 192, 0, stream>>>(qh, cosb, sinb, q_full);
    prep_kv<<<S_LEN, 192, 0, stream>>>(kvb, lkv, cosb, sinb, k_full, vt);

    flash_attn2<<<512, 256, 0, stream>>>(q_full, k_full, vt, attn);

    gemm_bf16<<<dim3(HIDDEN / 128, S_LEN / 128), 256, 0, stream>>>(attn, wo_bf, out,
        S_LEN, HIDDEN, NHEAD * V_D, 0);
}

// Round 6
// 274.254 us; speedup vs baseline: 2.5351x; 1.3658x over previous
//
#include <hip/hip_runtime.h>

typedef unsigned short u16;
typedef unsigned int u32;
typedef __attribute__((ext_vector_type(8))) short bf16x8;
typedef __attribute__((ext_vector_type(4))) float f32x4;
typedef __attribute__((ext_vector_type(16))) float f32x16;
typedef __attribute__((ext_vector_type(4))) unsigned short u16x4;

#define S_LEN 2048
#define HIDDEN 2048
#define NHEAD 16
#define QLORA 1536
#define KVLORA 512
#define NOPE_D 128
#define ROPE_D 64
#define V_D 128
#define HEAD_D 192
#define LOG2E 1.442695041f

// SOFTMAX_SCALE = 192^-0.5 * mscale^2, mscale = 0.1*ln(40)+1
__device__ __constant__ float SM_SCALE_C = (float)(0.07216878364870323 *
    ((0.1 * 3.6888794541139363 + 1.0) * (0.1 * 3.6888794541139363 + 1.0)));

__device__ inline u16 f2bf(float f) {
    union { float f; unsigned int u; } v; v.f = f;
    unsigned int r = v.u + 0x7FFFu + ((v.u >> 16) & 1u);
    return (u16)(r >> 16);
}
__device__ inline float bf2f(u16 b) {
    union { unsigned int u; float f; } v; v.u = ((unsigned int)b) << 16;
    return v.f;
}
__device__ inline void gload_lds16(const u16* g, u16* l) {
    __builtin_amdgcn_global_load_lds(
        (const __attribute__((address_space(1))) void*)g,
        (__attribute__((address_space(3))) void*)l, 16, 0, 0);
}

// ---------------- f32 -> bf16 convert ----------------
__global__ void cvt_f32_bf16(const float* __restrict__ in, u16* __restrict__ out, int n) {
    int i = (blockIdx.x * blockDim.x + threadIdx.x) * 4;
    if (i >= n) return;
    f32x4 v = *(const f32x4*)(in + i);
    u16x4 o;
    o[0] = f2bf(v[0]); o[1] = f2bf(v[1]); o[2] = f2bf(v[2]); o[3] = f2bf(v[3]);
    *(u16x4*)(out + i) = o;
}

// ---------------- weight dequant: f32 [N,K] * blockscale -> bf16 [N,K] ----------------
__global__ __launch_bounds__(64)
void dequant_w(const float* __restrict__ W, const float* __restrict__ Sc,
               u16* __restrict__ out, int N, int K, int sc_cols) {
    int k = (blockIdx.x * 64 + threadIdx.x) * 8;
    int n = blockIdx.y;
    if (k >= K) return;
    float sc = Sc[(n >> 7) * sc_cols + (k >> 7)];
    f32x4 v0 = *(const f32x4*)(W + (size_t)n * K + k);
    f32x4 v1 = *(const f32x4*)(W + (size_t)n * K + k + 4);
    bf16x8 o;
    #pragma unroll
    for (int i = 0; i < 4; ++i) {
        o[i]     = (short)f2bf(v0[i] * sc);
        o[i + 4] = (short)f2bf(v1[i] * sc);
    }
    *(bf16x8*)(out + (size_t)n * K + k) = o;
}

// ---------------- rmsnorm: bf16 in (strided), bf16 out ----------------
__global__ __launch_bounds__(256)
void rmsnorm_k(const u16* __restrict__ in, const float* __restrict__ w,
               u16* __restrict__ out, int D, int istride, int ostride) {
    int row = blockIdx.x;
    const u16* x = in + (size_t)row * istride;
    float ss = 0.f;
    for (int d = threadIdx.x; d < D; d += 256) { float v = bf2f(x[d]); ss += v * v; }
    #pragma unroll
    for (int off = 1; off < 64; off <<= 1) ss += __shfl_xor(ss, off, 64);
    __shared__ float red[4];
    if ((threadIdx.x & 63) == 0) red[threadIdx.x >> 6] = ss;
    __syncthreads();
    float tot = red[0] + red[1] + red[2] + red[3];
    float rs = rsqrtf(tot / (float)D + 1e-6f);
    for (int d = threadIdx.x; d < D; d += 256)
        out[(size_t)row * ostride + d] = f2bf(bf2f(x[d]) * rs * w[d]);
}

// ---------------- bf16 GEMM (m97 structure): C[M,N] = A[M,K] @ W[N,K]^T ----------------
__global__ __launch_bounds__(256)
void gemm_bf16(const u16* __restrict__ A, const u16* __restrict__ W,
               void* __restrict__ C, int M, int N, int K, int obf) {
    __shared__ u16 As[128 * 64];
    __shared__ u16 Ws[128 * 64];
    const int tid = threadIdx.x;
    const int lane = tid & 63;
    const int wv = tid >> 6;
    const int wm = wv >> 1, wn = wv & 1;
    const int bm = blockIdx.y * 128, bn = blockIdx.x * 128;
    const int lr = lane & 15, lk = lane >> 4;
    const int srow = lane >> 3;
    const int schunk = lane & 7;

    f32x4 acc[4][4] = {};

    for (int k0 = 0; k0 < K; k0 += 64) {
        __syncthreads();
        #pragma unroll
        for (int i = 0; i < 4; ++i) {
            int t = (wv * 4 + i) * 8 + srow;
            int cs = (schunk ^ (t & 7)) << 3;
            gload_lds16(A + (size_t)(bm + t) * K + k0 + cs, &As[(wv * 4 + i) * 512]);
            gload_lds16(W + (size_t)(bn + t) * K + k0 + cs, &Ws[(wv * 4 + i) * 512]);
        }
        __syncthreads();
        #pragma unroll
        for (int kh = 0; kh < 2; ++kh) {
            bf16x8 af[4], bfr[4];
            #pragma unroll
            for (int mi = 0; mi < 4; ++mi) {
                int r = wm * 64 + mi * 16 + lr;
                af[mi] = *(const bf16x8*)&As[r * 64 + (((kh * 4 + lk) ^ (lr & 7)) << 3)];
            }
            #pragma unroll
            for (int ni = 0; ni < 4; ++ni) {
                int r = wn * 64 + ni * 16 + lr;
                bfr[ni] = *(const bf16x8*)&Ws[r * 64 + (((kh * 4 + lk) ^ (lr & 7)) << 3)];
            }
            #pragma unroll
            for (int mi = 0; mi < 4; ++mi)
                #pragma unroll
                for (int ni = 0; ni < 4; ++ni)
                    acc[mi][ni] = __builtin_amdgcn_mfma_f32_16x16x32_bf16(af[mi], bfr[ni], acc[mi][ni], 0, 0, 0);
        }
    }

    #pragma unroll
    for (int mi = 0; mi < 4; ++mi)
        #pragma unroll
        for (int ni = 0; ni < 4; ++ni)
            #pragma unroll
            for (int j = 0; j < 4; ++j) {
                int r = bm + wm * 64 + mi * 16 + lk * 4 + j;
                int c = bn + wn * 64 + ni * 16 + lr;
                if (c < N) {
                    if (obf) ((u16*)C)[(size_t)r * N + c] = f2bf(acc[mi][ni][j]);
                    else     ((float*)C)[(size_t)r * N + c] = acc[mi][ni][j];
                }
            }
}

// ---------------- Q prep -> MFMA fragment order ----------------
// qh: bf16 [S][NH*192]. out qfrag: [NH][S/32][12 frag][64 lane][8] bf16.
// Fragment kk, lane l: element Q[s0+(l&31)][kk*16 + (l>>5)*8 + j] (RoPE'd, scaled).
__global__ __launch_bounds__(256)
void prep_q_frag(const u16* __restrict__ qh, const float* __restrict__ cosb,
                 const float* __restrict__ sinb, u16* __restrict__ qfrag) {
    const int sblk = blockIdx.x, h = blockIdx.y;
    const float sm = SM_SCALE_C;
    #pragma unroll
    for (int c = 0; c < 3; ++c) {
        int idx = c * 256 + threadIdx.x;      // 0..767
        int kk = idx >> 6;                    // 0..11
        int lane = idx & 63;
        int s = sblk * 32 + (lane & 31);
        int d0 = kk * 16 + (lane >> 5) * 8;
        const u16* qp = qh + (size_t)s * (NHEAD * HEAD_D) + h * HEAD_D;
        bf16x8 x = *(const bf16x8*)(qp + d0);
        bf16x8 o;
        if (d0 < NOPE_D) {
            #pragma unroll
            for (int j = 0; j < 8; ++j) o[j] = (short)f2bf(bf2f((u16)x[j]) * sm);
        } else {
            int r0 = d0 - NOPE_D;
            bf16x8 rv = *(const bf16x8*)(qp + NOPE_D + ((r0 + 32) & 63));
            float sign = (r0 < 32) ? -1.f : 1.f;
            #pragma unroll
            for (int j = 0; j < 8; ++j) {
                float cs = cosb[s * ROPE_D + r0 + j];
                float sn = sinb[s * ROPE_D + r0 + j];
                float val = bf2f((u16)x[j]) * cs + sign * bf2f((u16)rv[j]) * sn;
                o[j] = (short)f2bf(val * sm);
            }
        }
        *(bf16x8*)(qfrag + (((size_t)h * 64 + sblk) * 12 + kk) * 512 + lane * 8) = o;
    }
}

// ---------------- K prep -> MFMA fragment order ----------------
// kvb: bf16 [S][NH*256] (nope+v); lkv: bf16 [S][576] (pe at 512..575).
// out kfrag: [NH][S/32][12][64][8] bf16, same fragment convention as Q.
__global__ __launch_bounds__(256)
void prep_k_frag(const u16* __restrict__ kvb, const u16* __restrict__ lkv,
                 const float* __restrict__ cosb, const float* __restrict__ sinb,
                 u16* __restrict__ kfrag) {
    const int sblk = blockIdx.x, h = blockIdx.y;
    #pragma unroll
    for (int c = 0; c < 3; ++c) {
        int idx = c * 256 + threadIdx.x;
        int kk = idx >> 6;
        int lane = idx & 63;
        int s = sblk * 32 + (lane & 31);
        int d0 = kk * 16 + (lane >> 5) * 8;
        bf16x8 o;
        if (d0 < NOPE_D) {
            o = *(const bf16x8*)(kvb + (size_t)s * (NHEAD * 256) + h * 256 + d0);
        } else {
            int r0 = d0 - NOPE_D;
            const u16* kp = lkv + (size_t)s * (KVLORA + ROPE_D) + KVLORA;
            bf16x8 x = *(const bf16x8*)(kp + r0);
            bf16x8 rv = *(const bf16x8*)(kp + ((r0 + 32) & 63));
            float sign = (r0 < 32) ? -1.f : 1.f;
            #pragma unroll
            for (int j = 0; j < 8; ++j) {
                float cs = cosb[s * ROPE_D + r0 + j];
                float sn = sinb[s * ROPE_D + r0 + j];
                o[j] = (short)f2bf(bf2f((u16)x[j]) * cs + sign * bf2f((u16)rv[j]) * sn);
            }
        }
        *(bf16x8*)(kfrag + (((size_t)h * 64 + sblk) * 12 + kk) * 512 + lane * 8) = o;
    }
}

// ---------------- V prep -> transposed MFMA fragment order ----------------
// out vfrag: [NH][S/32][8 frag][64 lane][8] bf16.
// Fragment fi=bb*2+h16, lane l: element V[s0 + h16*16 + (l>>5)*8 + j][bb*32 + (l&31)].
__global__ __launch_bounds__(256)
void prep_v_frag(const u16* __restrict__ kvb, u16* __restrict__ vfrag) {
    __shared__ u16 Vs[32][136];
    const int sblk = blockIdx.x, h = blockIdx.y;
    // stage full 32x128 V tile: 512 chunk-writes of 8 elems (was the round-5 bug:
    // only half the columns were staged)
    #pragma unroll
    for (int it = 0; it < 2; ++it) {
        int idx = it * 256 + threadIdx.x;     // 0..511
        int r = idx >> 4;                     // 0..31
        int c8 = (idx & 15) * 8;              // 0..120
        int s = sblk * 32 + r;
        *(bf16x8*)&Vs[r][c8] = *(const bf16x8*)(kvb + (size_t)s * (NHEAD * 256) + h * 256 + NOPE_D + c8);
    }
    __syncthreads();
    #pragma unroll
    for (int it = 0; it < 2; ++it) {
        int idx = it * 256 + threadIdx.x;     // 0..511
        int fi = idx >> 6;                    // 0..7
        int lane = idx & 63;
        int bb = fi >> 1, h16 = fi & 1;
        int col = bb * 32 + (lane & 31);
        int row0 = h16 * 16 + (lane >> 5) * 8;
        bf16x8 o;
        #pragma unroll
        for (int j = 0; j < 8; ++j) o[j] = (short)Vs[row0 + j][col];
        *(bf16x8*)(vfrag + (((size_t)h * 64 + sblk) * 8 + fi) * 512 + lane * 8) = o;
    }
}

// ---------------- causal flash attention v4: fragment-order loads ----------
// qfrag/kfrag: [NH][64][12][64][8]; vfrag: [NH][64][8][64][8]; attn: bf16 [S][NH*128]
// Grid: 512 blocks x 256 thr. block b: q-tile t = 63-(b>>3), head pair (b&7).
// wave wv: head = 2*(b&7)+(wv>>1), kv-half = wv&1; halves merged via LDS.
// Every global load is a contiguous 1KB wave load (lane*16B within the fragment).
__global__ __launch_bounds__(256, 2)
void flash_attn2(const u16* __restrict__ qfrag, const u16* __restrict__ kfrag,
                 const u16* __restrict__ vfrag, u16* __restrict__ attn) {
    __shared__ float OB[2][128][32];   // [pair][dv][q]
    __shared__ float MB[2][2][32];     // [pair][{m,l}][q]

    const int tid = threadIdx.x, lane = tid & 63, wv = tid >> 6;
    const int b = blockIdx.x;
    const int t = 63 - (b >> 3);
    const int pr = wv >> 1;
    const int half = wv & 1;
    const int h = ((b & 7) << 1) | pr;
    const int q0 = t * 32;
    const int lq = lane & 31;
    const int hi = lane >> 5;

    const int n = t + 1;
    const int mid = (n + 1) >> 1;
    const int s_lo = half ? mid : 0;
    const int s_hi = half ? n : mid;

    // persistent Q B-fragments (coalesced 1KB loads)
    bf16x8 qfr[12];
    {
        const u16* qb = qfrag + (((size_t)h * 64 + t) * 12) * 512 + lane * 8;
        #pragma unroll
        for (int kk = 0; kk < 12; ++kk)
            qfr[kk] = *(const bf16x8*)(qb + kk * 512);
    }

    const u16* kfb = kfrag + ((size_t)h * 64 * 12) * 512 + lane * 8;
    const u16* vfb = vfrag + ((size_t)h * 64 * 8) * 512 + lane * 8;

    f32x16 oa[4] = {};
    float mrun = -3.0e38f, lrun = 0.f;

    // preload K fragments for first subtile
    bf16x8 kcur[12];
    {
        int psub = (s_lo < s_hi) ? s_lo : (n - 1);
        const u16* kp = kfb + (size_t)psub * 12 * 512;
        #pragma unroll
        for (int kk = 0; kk < 12; ++kk)
            kcur[kk] = *(const bf16x8*)(kp + kk * 512);
    }

    for (int sub = s_lo; sub < s_hi; ++sub) {
        // ---- QK^T (swapped): S^T[kv,q] ----
        f32x16 s0 = {}, s1 = {};
        __builtin_amdgcn_s_setprio(1);
        #pragma unroll
        for (int kk = 0; kk < 12; kk += 2) {
            s0 = __builtin_amdgcn_mfma_f32_32x32x16_bf16(kcur[kk], qfr[kk], s0, 0, 0, 0);
            s1 = __builtin_amdgcn_mfma_f32_32x32x16_bf16(kcur[kk + 1], qfr[kk + 1], s1, 0, 0, 0);
        }
        __builtin_amdgcn_s_setprio(0);
        // ---- T14: kcur dead -> issue K loads for NEXT subtile now ----
        {
            int nsub = (sub + 1 < s_hi) ? sub + 1 : sub;
            const u16* kp = kfb + (size_t)nsub * 12 * 512;
            #pragma unroll
            for (int kk = 0; kk < 12; ++kk)
                kcur[kk] = *(const bf16x8*)(kp + kk * 512);
        }
        // ---- V loads for CURRENT subtile ----
        bf16x8 va[8];
        {
            const u16* vp = vfb + (size_t)sub * 8 * 512;
            #pragma unroll
            for (int fi = 0; fi < 8; ++fi)
                va[fi] = *(const bf16x8*)(vp + fi * 512);
        }
        f32x16 sv = s0 + s1;
        // causal mask (diagonal subtile only)
        if (sub == t) {
            #pragma unroll
            for (int r = 0; r < 16; ++r) {
                int krow = (r & 3) + 8 * (r >> 2) + 4 * hi;
                if (krow > lq) sv[r] = -3.0e38f;
            }
        }
        // ---- row max (lane-local in q) ----
        float tm = sv[0];
        #pragma unroll
        for (int r = 1; r < 16; ++r) tm = fmaxf(tm, sv[r]);
        tm = fmaxf(tm, __shfl_xor(tm, 32, 64));
        // defer-max
        if (!__all(tm - mrun <= 8.f)) {
            float mn = fmaxf(mrun, tm);
            float scl = exp2f((mrun - mn) * LOG2E);
            mrun = mn;
            lrun *= scl;
            #pragma unroll
            for (int bb = 0; bb < 4; ++bb)
                #pragma unroll
                for (int r = 0; r < 16; ++r) oa[bb][r] *= scl;
        }
        // ---- P = exp(s - m), row sum ----
        float p[16];
        float psum = 0.f;
        #pragma unroll
        for (int r = 0; r < 16; ++r) {
            p[r] = exp2f((sv[r] - mrun) * LOG2E);
            psum += p[r];
        }
        psum += __shfl_xor(psum, 32, 64);
        lrun += psum;
        // ---- pack P to bf16, redistribute across lane halves ----
        u32 pw[8], sw[8];
        #pragma unroll
        for (int i = 0; i < 8; ++i)
            pw[i] = (u32)f2bf(p[2 * i]) | ((u32)f2bf(p[2 * i + 1]) << 16);
        #pragma unroll
        for (int i = 0; i < 8; ++i)
            sw[i] = (u32)__shfl_xor((int)pw[i], 32, 64);
        union { u32 w[4]; bf16x8 v; } bf0, bf1;
        bf0.w[0] = hi ? sw[2] : pw[0];
        bf0.w[1] = hi ? sw[3] : pw[1];
        bf0.w[2] = hi ? pw[2] : sw[0];
        bf0.w[3] = hi ? pw[3] : sw[1];
        bf1.w[0] = hi ? sw[6] : pw[4];
        bf1.w[1] = hi ? sw[7] : pw[5];
        bf1.w[2] = hi ? pw[6] : sw[4];
        bf1.w[3] = hi ? pw[7] : sw[5];
        // ---- PV: O^T = mfma(A=V^T, B=P^T) ----
        __builtin_amdgcn_s_setprio(1);
        #pragma unroll
        for (int bb = 0; bb < 4; ++bb) {
            oa[bb] = __builtin_amdgcn_mfma_f32_32x32x16_bf16(va[bb * 2],     bf0.v, oa[bb], 0, 0, 0);
            oa[bb] = __builtin_amdgcn_mfma_f32_32x32x16_bf16(va[bb * 2 + 1], bf1.v, oa[bb], 0, 0, 0);
        }
        __builtin_amdgcn_s_setprio(0);
    }

    // ---- merge the two kv-halves ----
    if (half) {
        #pragma unroll
        for (int bb = 0; bb < 4; ++bb)
            #pragma unroll
            for (int r = 0; r < 16; ++r) {
                int dv = bb * 32 + (r & 3) + 8 * (r >> 2) + 4 * hi;
                OB[pr][dv][lq] = oa[bb][r];
            }
        if (lane < 32) {
            MB[pr][0][lane] = mrun;
            MB[pr][1][lane] = lrun;
        }
    }
    __syncthreads();
    if (!half) {
        float mB = MB[pr][0][lq];
        float lB = MB[pr][1][lq];
        float M = fmaxf(mrun, mB);
        float eA = exp2f((mrun - M) * LOG2E);
        float eB = exp2f((mB - M) * LOG2E);
        float L = lrun * eA + lB * eB;
        float inv = 1.0f / L;
        u16* ob = attn + (size_t)(q0 + lq) * (NHEAD * V_D) + h * V_D;
        #pragma unroll
        for (int bb = 0; bb < 4; ++bb)
            #pragma unroll
            for (int rq = 0; rq < 4; ++rq) {
                u16x4 pk;
                #pragma unroll
                for (int rb = 0; rb < 4; ++rb) {
                    int r = rq * 4 + rb;
                    int dv = bb * 32 + rb + 8 * rq + 4 * hi;
                    float o = (oa[bb][r] * eA + OB[pr][dv][lq] * eB) * inv;
                    pk[rb] = f2bf(o);
                }
                *(u16x4*)(ob + bb * 32 + 8 * rq + 4 * hi) = pk;
            }
    }
}

extern "C" void kernel_launch(void* const* d_in, const int* in_sizes, int n_in,
                              void* d_out, int out_size, void* d_ws, size_t ws_size,
                              hipStream_t stream) {
    const float* hs    = (const float*)d_in[0];
    const float* wq_a  = (const float*)d_in[1];
    const float* sq_a  = (const float*)d_in[2];
    const float* wq_b  = (const float*)d_in[3];
    const float* sq_b  = (const float*)d_in[4];
    const float* wkv_a = (const float*)d_in[5];
    const float* skv_a = (const float*)d_in[6];
    const float* wkv_b = (const float*)d_in[7];
    const float* skv_b = (const float*)d_in[8];
    const float* wo    = (const float*)d_in[9];
    const float* so    = (const float*)d_in[10];
    const float* q_ln  = (const float*)d_in[11];
    const float* kv_ln = (const float*)d_in[12];
    const float* cosb  = (const float*)d_in[13];
    const float* sinb  = (const float*)d_in[14];
    float* out = (float*)d_out;

    char* ws = (char*)d_ws;
    size_t off = 0;
    auto alloc = [&](size_t bytes) -> void* {
        void* p = ws + off; off += (bytes + 255) & ~(size_t)255; return p;
    };
    u16* hs_bf  = (u16*)alloc((size_t)S_LEN * HIDDEN * 2);
    u16* lq     = (u16*)alloc((size_t)S_LEN * QLORA * 2);
    u16* lqn    = (u16*)alloc((size_t)S_LEN * QLORA * 2);
    u16* qh     = (u16*)alloc((size_t)S_LEN * NHEAD * HEAD_D * 2);
    u16* lkv    = (u16*)alloc((size_t)S_LEN * (KVLORA + ROPE_D) * 2);
    u16* kvn    = (u16*)alloc((size_t)S_LEN * KVLORA * 2);
    u16* kvb    = (u16*)alloc((size_t)S_LEN * NHEAD * 256 * 2);
    u16* attn   = (u16*)alloc((size_t)S_LEN * NHEAD * V_D * 2);
    u16* qfrag  = (u16*)alloc((size_t)NHEAD * 64 * 12 * 512 * 2);
    u16* kfrag  = (u16*)alloc((size_t)NHEAD * 64 * 12 * 512 * 2);
    u16* vfrag  = (u16*)alloc((size_t)NHEAD * 64 * 8 * 512 * 2);
    u16* wqa_bf  = (u16*)alloc((size_t)QLORA * HIDDEN * 2);
    u16* wqb_bf  = (u16*)alloc((size_t)(NHEAD * HEAD_D) * QLORA * 2);
    u16* wkva_bf = (u16*)alloc((size_t)640 * HIDDEN * 2);
    u16* wkvb_bf = (u16*)alloc((size_t)(NHEAD * 256) * KVLORA * 2);
    u16* wo_bf   = (u16*)alloc((size_t)HIDDEN * (NHEAD * V_D) * 2);

    cvt_f32_bf16<<<(S_LEN * HIDDEN / 4 + 255) / 256, 256, 0, stream>>>(hs, hs_bf, S_LEN * HIDDEN);

    dequant_w<<<dim3(HIDDEN / 512, QLORA), 64, 0, stream>>>(wq_a, sq_a, wqa_bf, QLORA, HIDDEN, 16);
    dequant_w<<<dim3(QLORA / 512, NHEAD * HEAD_D), 64, 0, stream>>>(wq_b, sq_b, wqb_bf, NHEAD * HEAD_D, QLORA, 12);
    dequant_w<<<dim3(HIDDEN / 512, KVLORA + ROPE_D), 64, 0, stream>>>(wkv_a, skv_a, wkva_bf, KVLORA + ROPE_D, HIDDEN, 16);
    dequant_w<<<dim3(KVLORA / 512, NHEAD * 256), 64, 0, stream>>>(wkv_b, skv_b, wkvb_bf, NHEAD * 256, KVLORA, 4);
    dequant_w<<<dim3((NHEAD * V_D) / 512, HIDDEN), 64, 0, stream>>>(wo, so, wo_bf, HIDDEN, NHEAD * V_D, 16);

    gemm_bf16<<<dim3(QLORA / 128, S_LEN / 128), 256, 0, stream>>>(hs_bf, wqa_bf, lq,
        S_LEN, QLORA, HIDDEN, 1);
    rmsnorm_k<<<S_LEN, 256, 0, stream>>>(lq, q_ln, lqn, QLORA, QLORA, QLORA);
    gemm_bf16<<<dim3(NHEAD * HEAD_D / 128, S_LEN / 128), 256, 0, stream>>>(lqn, wqb_bf, qh,
        S_LEN, NHEAD * HEAD_D, QLORA, 1);
    gemm_bf16<<<dim3(5, S_LEN / 128), 256, 0, stream>>>(hs_bf, wkva_bf, lkv,
        S_LEN, KVLORA + ROPE_D, HIDDEN, 1);
    rmsnorm_k<<<S_LEN, 256, 0, stream>>>(lkv, kv_ln, kvn, KVLORA, KVLORA + ROPE_D, KVLORA);
    gemm_bf16<<<dim3(NHEAD * 256 / 128, S_LEN / 128), 256, 0, stream>>>(kvn, wkvb_bf, kvb,
        S_LEN, NHEAD * 256, KVLORA, 1);

    prep_q_frag<<<dim3(64, NHEAD), 256, 0, stream>>>(qh, cosb, sinb, qfrag);
    prep_k_frag<<<dim3(64, NHEAD), 256, 0, stream>>>(kvb, lkv, cosb, sinb, kfrag);
    prep_v_frag<<<dim3(64, NHEAD), 256, 0, stream>>>(kvb, vfrag);

    flash_attn2<<<512, 256, 0, stream>>>(qfrag, kfrag, vfrag, attn);

    gemm_bf16<<<dim3(HIDDEN / 128, S_LEN / 128), 256, 0, stream>>>(attn, wo_bf, out,
        S_LEN, HIDDEN, NHEAD * V_D, 0);
}

// Round 7
// 246.668 us; speedup vs baseline: 2.8186x; 1.1118x over previous
//
#include <hip/hip_runtime.h>

typedef unsigned short u16;
typedef unsigned int u32;
typedef __attribute__((ext_vector_type(8))) short bf16x8;
typedef __attribute__((ext_vector_type(4))) float f32x4;
typedef __attribute__((ext_vector_type(16))) float f32x16;
typedef __attribute__((ext_vector_type(4))) unsigned short u16x4;

#define S_LEN 2048
#define HIDDEN 2048
#define NHEAD 16
#define QLORA 1536
#define KVLORA 512
#define NOPE_D 128
#define ROPE_D 64
#define V_D 128
#define HEAD_D 192
#define NCOMB 2176   // QLORA + KVLORA + ROPE_D + 64 pad (N=17*128)
#define LOG2E 1.442695041f

// SOFTMAX_SCALE = 192^-0.5 * mscale^2, mscale = 0.1*ln(40)+1
__device__ __constant__ float SM_SCALE_C = (float)(0.07216878364870323 *
    ((0.1 * 3.6888794541139363 + 1.0) * (0.1 * 3.6888794541139363 + 1.0)));

__device__ inline u16 f2bf(float f) {
    union { float f; unsigned int u; } v; v.f = f;
    unsigned int r = v.u + 0x7FFFu + ((v.u >> 16) & 1u);
    return (u16)(r >> 16);
}
__device__ inline float bf2f(u16 b) {
    union { unsigned int u; float f; } v; v.u = ((unsigned int)b) << 16;
    return v.f;
}
__device__ inline void gload_lds16(const u16* g, u16* l) {
    __builtin_amdgcn_global_load_lds(
        (const __attribute__((address_space(1))) void*)g,
        (__attribute__((address_space(3))) void*)l, 16, 0, 0);
}

// ---------------- f32 -> bf16 convert ----------------
__global__ void cvt_f32_bf16(const float* __restrict__ in, u16* __restrict__ out, int n) {
    int i = (blockIdx.x * blockDim.x + threadIdx.x) * 4;
    if (i >= n) return;
    f32x4 v = *(const f32x4*)(in + i);
    u16x4 o;
    o[0] = f2bf(v[0]); o[1] = f2bf(v[1]); o[2] = f2bf(v[2]); o[3] = f2bf(v[3]);
    *(u16x4*)(out + i) = o;
}

// ---------------- weight dequant: f32 [N,K] * blockscale -> bf16 [N,K] ----------------
__global__ __launch_bounds__(64)
void dequant_w(const float* __restrict__ W, const float* __restrict__ Sc,
               u16* __restrict__ out, int N, int K, int sc_cols) {
    int k = (blockIdx.x * 64 + threadIdx.x) * 8;
    int n = blockIdx.y;
    if (k >= K) return;
    float sc = Sc[(n >> 7) * sc_cols + (k >> 7)];
    f32x4 v0 = *(const f32x4*)(W + (size_t)n * K + k);
    f32x4 v1 = *(const f32x4*)(W + (size_t)n * K + k + 4);
    bf16x8 o;
    #pragma unroll
    for (int i = 0; i < 4; ++i) {
        o[i]     = (short)f2bf(v0[i] * sc);
        o[i + 4] = (short)f2bf(v1[i] * sc);
    }
    *(bf16x8*)(out + (size_t)n * K + k) = o;
}

// ---------------- bf16 GEMM (m97 structure, split-K): C = A[M,Ktot] @ W[N,Ktot]^T ----
// blockIdx.z = K-split index; computes k in [z*Ksub, z*Ksub+Ksub).
// mode 0: f32 direct; mode 1: bf16 direct; mode 2: f32 partial at C + z*M*N.
__global__ __launch_bounds__(256)
void gemm_bf16(const u16* __restrict__ A, const u16* __restrict__ W,
               void* __restrict__ C, int M, int N, int Ktot, int Ksub, int mode) {
    __shared__ u16 As[128 * 64];
    __shared__ u16 Ws[128 * 64];
    const int tid = threadIdx.x;
    const int lane = tid & 63;
    const int wv = tid >> 6;
    const int wm = wv >> 1, wn = wv & 1;
    const int bm = blockIdx.y * 128, bn = blockIdx.x * 128;
    const int lr = lane & 15, lk = lane >> 4;
    const int srow = lane >> 3;
    const int schunk = lane & 7;

    f32x4 acc[4][4] = {};

    const int kbeg = blockIdx.z * Ksub;
    const int kend = kbeg + Ksub;
    for (int k0 = kbeg; k0 < kend; k0 += 64) {
        __syncthreads();
        #pragma unroll
        for (int i = 0; i < 4; ++i) {
            int t = (wv * 4 + i) * 8 + srow;
            int cs = (schunk ^ (t & 7)) << 3;
            gload_lds16(A + (size_t)(bm + t) * Ktot + k0 + cs, &As[(wv * 4 + i) * 512]);
            gload_lds16(W + (size_t)(bn + t) * Ktot + k0 + cs, &Ws[(wv * 4 + i) * 512]);
        }
        __syncthreads();
        #pragma unroll
        for (int kh = 0; kh < 2; ++kh) {
            bf16x8 af[4], bfr[4];
            #pragma unroll
            for (int mi = 0; mi < 4; ++mi) {
                int r = wm * 64 + mi * 16 + lr;
                af[mi] = *(const bf16x8*)&As[r * 64 + (((kh * 4 + lk) ^ (lr & 7)) << 3)];
            }
            #pragma unroll
            for (int ni = 0; ni < 4; ++ni) {
                int r = wn * 64 + ni * 16 + lr;
                bfr[ni] = *(const bf16x8*)&Ws[r * 64 + (((kh * 4 + lk) ^ (lr & 7)) << 3)];
            }
            #pragma unroll
            for (int mi = 0; mi < 4; ++mi)
                #pragma unroll
                for (int ni = 0; ni < 4; ++ni)
                    acc[mi][ni] = __builtin_amdgcn_mfma_f32_16x16x32_bf16(af[mi], bfr[ni], acc[mi][ni], 0, 0, 0);
        }
    }

    float* Pf = (mode == 2) ? ((float*)C + (size_t)blockIdx.z * M * N) : (float*)C;
    #pragma unroll
    for (int mi = 0; mi < 4; ++mi)
        #pragma unroll
        for (int ni = 0; ni < 4; ++ni)
            #pragma unroll
            for (int j = 0; j < 4; ++j) {
                int r = bm + wm * 64 + mi * 16 + lk * 4 + j;
                int c = bn + wn * 64 + ni * 16 + lr;
                if (c < N) {
                    if (mode == 1) ((u16*)C)[(size_t)r * N + c] = f2bf(acc[mi][ni][j]);
                    else           Pf[(size_t)r * N + c] = acc[mi][ni][j];
                }
            }
}

// ---------------- fused split-K reduce + dual rmsnorm for the comb GEMM ----------------
// P: f32 [2][S][NCOMB]. cols 0..1535 -> rmsnorm(q_ln) -> lqn bf16 [S][1536]
// cols 1536..2047 -> rmsnorm(kv_ln) -> kvn bf16 [S][512]; cols 2048..2111 -> kpe bf16 [S][64]
// cols 2112..2175 are garbage (unwritten weight rows) and are never consumed.
__global__ __launch_bounds__(256)
void reduce_rms_comb(const float* __restrict__ P,
                     const float* __restrict__ q_ln, const float* __restrict__ kv_ln,
                     u16* __restrict__ lqn, u16* __restrict__ kvn, u16* __restrict__ kpe) {
    __shared__ float vbuf[NCOMB];
    __shared__ float r2[2][4];
    const int row = blockIdx.x;
    const float* p0 = P + (size_t)row * NCOMB;
    const float* p1 = p0 + (size_t)S_LEN * NCOMB;
    float ssq = 0.f, ssk = 0.f;
    for (int c = threadIdx.x * 4; c < NCOMB; c += 1024) {
        f32x4 a = *(const f32x4*)(p0 + c);
        f32x4 b = *(const f32x4*)(p1 + c);
        f32x4 v = a + b;
        *(f32x4*)&vbuf[c] = v;
        float s = v[0] * v[0] + v[1] * v[1] + v[2] * v[2] + v[3] * v[3];
        if (c < QLORA) ssq += s;
        else if (c < QLORA + KVLORA) ssk += s;
    }
    #pragma unroll
    for (int off = 1; off < 64; off <<= 1) {
        ssq += __shfl_xor(ssq, off, 64);
        ssk += __shfl_xor(ssk, off, 64);
    }
    if ((threadIdx.x & 63) == 0) {
        r2[0][threadIdx.x >> 6] = ssq;
        r2[1][threadIdx.x >> 6] = ssk;
    }
    __syncthreads();
    float rsq = rsqrtf((r2[0][0] + r2[0][1] + r2[0][2] + r2[0][3]) / (float)QLORA + 1e-6f);
    float rsk = rsqrtf((r2[1][0] + r2[1][1] + r2[1][2] + r2[1][3]) / (float)KVLORA + 1e-6f);
    for (int c = threadIdx.x * 4; c < NCOMB; c += 1024) {
        f32x4 v = *(const f32x4*)&vbuf[c];
        u16x4 o;
        if (c < QLORA) {
            #pragma unroll
            for (int j = 0; j < 4; ++j) o[j] = f2bf(v[j] * rsq * q_ln[c + j]);
            *(u16x4*)(lqn + (size_t)row * QLORA + c) = o;
        } else if (c < QLORA + KVLORA) {
            int cc = c - QLORA;
            #pragma unroll
            for (int j = 0; j < 4; ++j) o[j] = f2bf(v[j] * rsk * kv_ln[cc + j]);
            *(u16x4*)(kvn + (size_t)row * KVLORA + cc) = o;
        } else if (c < QLORA + KVLORA + ROPE_D) {
            int cc = c - QLORA - KVLORA;
            #pragma unroll
            for (int j = 0; j < 4; ++j) o[j] = f2bf(v[j]);
            *(u16x4*)(kpe + (size_t)row * ROPE_D + cc) = o;
        }
    }
}

// ---------------- Q prep from split-K partials -> MFMA fragment order ----------------
// P: f32 [2][S][3072]. out qfrag: [NH][S/32][12 frag][64 lane][8] bf16.
__global__ __launch_bounds__(256)
void prep_q_frag_red(const float* __restrict__ P, const float* __restrict__ cosb,
                     const float* __restrict__ sinb, u16* __restrict__ qfrag) {
    const int sblk = blockIdx.x, h = blockIdx.y;
    const float sm = SM_SCALE_C;
    #pragma unroll
    for (int c = 0; c < 3; ++c) {
        int idx = c * 256 + threadIdx.x;      // 0..767
        int kk = idx >> 6;                    // 0..11
        int lane = idx & 63;
        int s = sblk * 32 + (lane & 31);
        int d0 = kk * 16 + (lane >> 5) * 8;
        const float* p0 = P + (size_t)s * (NHEAD * HEAD_D) + h * HEAD_D;
        const float* p1 = p0 + (size_t)S_LEN * (NHEAD * HEAD_D);
        bf16x8 o;
        if (d0 < NOPE_D) {
            f32x4 a0 = *(const f32x4*)(p0 + d0), a1 = *(const f32x4*)(p0 + d0 + 4);
            f32x4 b0 = *(const f32x4*)(p1 + d0), b1 = *(const f32x4*)(p1 + d0 + 4);
            #pragma unroll
            for (int j = 0; j < 4; ++j) {
                o[j]     = (short)f2bf((a0[j] + b0[j]) * sm);
                o[j + 4] = (short)f2bf((a1[j] + b1[j]) * sm);
            }
        } else {
            int r0 = d0 - NOPE_D;
            int rp = (r0 + 32) & 63;
            float x[8], rv[8];
            {
                f32x4 a0 = *(const f32x4*)(p0 + d0), a1 = *(const f32x4*)(p0 + d0 + 4);
                f32x4 b0 = *(const f32x4*)(p1 + d0), b1 = *(const f32x4*)(p1 + d0 + 4);
                #pragma unroll
                for (int j = 0; j < 4; ++j) { x[j] = a0[j] + b0[j]; x[j + 4] = a1[j] + b1[j]; }
            }
            {
                f32x4 a0 = *(const f32x4*)(p0 + NOPE_D + rp), a1 = *(const f32x4*)(p0 + NOPE_D + rp + 4);
                f32x4 b0 = *(const f32x4*)(p1 + NOPE_D + rp), b1 = *(const f32x4*)(p1 + NOPE_D + rp + 4);
                #pragma unroll
                for (int j = 0; j < 4; ++j) { rv[j] = a0[j] + b0[j]; rv[j + 4] = a1[j] + b1[j]; }
            }
            float sign = (r0 < 32) ? -1.f : 1.f;
            #pragma unroll
            for (int j = 0; j < 8; ++j) {
                float cs = cosb[s * ROPE_D + r0 + j];
                float sn = sinb[s * ROPE_D + r0 + j];
                o[j] = (short)f2bf((x[j] * cs + sign * rv[j] * sn) * sm);
            }
        }
        *(bf16x8*)(qfrag + (((size_t)h * 64 + sblk) * 12 + kk) * 512 + lane * 8) = o;
    }
}

// ---------------- split-K reduce for the final output (f32) ----------------
__global__ void reduce_out(const float* __restrict__ P, float* __restrict__ out, int n) {
    int i = (blockIdx.x * blockDim.x + threadIdx.x) * 4;
    if (i >= n) return;
    f32x4 a = *(const f32x4*)(P + i);
    f32x4 b = *(const f32x4*)(P + (size_t)n + i);
    *(f32x4*)(out + i) = a + b;
}

// ---------------- K prep -> MFMA fragment order ----------------
// kvb: bf16 [S][NH*256]; kpe: bf16 [S][64] (raw k_pe, RoPE applied here).
__global__ __launch_bounds__(256)
void prep_k_frag(const u16* __restrict__ kvb, const u16* __restrict__ kpe,
                 const float* __restrict__ cosb, const float* __restrict__ sinb,
                 u16* __restrict__ kfrag) {
    const int sblk = blockIdx.x, h = blockIdx.y;
    #pragma unroll
    for (int c = 0; c < 3; ++c) {
        int idx = c * 256 + threadIdx.x;
        int kk = idx >> 6;
        int lane = idx & 63;
        int s = sblk * 32 + (lane & 31);
        int d0 = kk * 16 + (lane >> 5) * 8;
        bf16x8 o;
        if (d0 < NOPE_D) {
            o = *(const bf16x8*)(kvb + (size_t)s * (NHEAD * 256) + h * 256 + d0);
        } else {
            int r0 = d0 - NOPE_D;
            const u16* kp = kpe + (size_t)s * ROPE_D;
            bf16x8 x = *(const bf16x8*)(kp + r0);
            bf16x8 rv = *(const bf16x8*)(kp + ((r0 + 32) & 63));
            float sign = (r0 < 32) ? -1.f : 1.f;
            #pragma unroll
            for (int j = 0; j < 8; ++j) {
                float cs = cosb[s * ROPE_D + r0 + j];
                float sn = sinb[s * ROPE_D + r0 + j];
                o[j] = (short)f2bf(bf2f((u16)x[j]) * cs + sign * bf2f((u16)rv[j]) * sn);
            }
        }
        *(bf16x8*)(kfrag + (((size_t)h * 64 + sblk) * 12 + kk) * 512 + lane * 8) = o;
    }
}

// ---------------- V prep -> transposed MFMA fragment order ----------------
__global__ __launch_bounds__(256)
void prep_v_frag(const u16* __restrict__ kvb, u16* __restrict__ vfrag) {
    __shared__ u16 Vs[32][136];
    const int sblk = blockIdx.x, h = blockIdx.y;
    #pragma unroll
    for (int it = 0; it < 2; ++it) {
        int idx = it * 256 + threadIdx.x;     // 0..511
        int r = idx >> 4;                     // 0..31
        int c8 = (idx & 15) * 8;              // 0..120
        int s = sblk * 32 + r;
        *(bf16x8*)&Vs[r][c8] = *(const bf16x8*)(kvb + (size_t)s * (NHEAD * 256) + h * 256 + NOPE_D + c8);
    }
    __syncthreads();
    #pragma unroll
    for (int it = 0; it < 2; ++it) {
        int idx = it * 256 + threadIdx.x;     // 0..511
        int fi = idx >> 6;                    // 0..7
        int lane = idx & 63;
        int bb = fi >> 1, h16 = fi & 1;
        int col = bb * 32 + (lane & 31);
        int row0 = h16 * 16 + (lane >> 5) * 8;
        bf16x8 o;
        #pragma unroll
        for (int j = 0; j < 8; ++j) o[j] = (short)Vs[row0 + j][col];
        *(bf16x8*)(vfrag + (((size_t)h * 64 + sblk) * 8 + fi) * 512 + lane * 8) = o;
    }
}

// ---------------- causal flash attention v4: fragment-order loads ----------
__global__ __launch_bounds__(256, 2)
void flash_attn2(const u16* __restrict__ qfrag, const u16* __restrict__ kfrag,
                 const u16* __restrict__ vfrag, u16* __restrict__ attn) {
    __shared__ float OB[2][128][32];   // [pair][dv][q]
    __shared__ float MB[2][2][32];     // [pair][{m,l}][q]

    const int tid = threadIdx.x, lane = tid & 63, wv = tid >> 6;
    const int b = blockIdx.x;
    const int t = 63 - (b >> 3);
    const int pr = wv >> 1;
    const int half = wv & 1;
    const int h = ((b & 7) << 1) | pr;
    const int q0 = t * 32;
    const int lq = lane & 31;
    const int hi = lane >> 5;

    const int n = t + 1;
    const int mid = (n + 1) >> 1;
    const int s_lo = half ? mid : 0;
    const int s_hi = half ? n : mid;

    bf16x8 qfr[12];
    {
        const u16* qb = qfrag + (((size_t)h * 64 + t) * 12) * 512 + lane * 8;
        #pragma unroll
        for (int kk = 0; kk < 12; ++kk)
            qfr[kk] = *(const bf16x8*)(qb + kk * 512);
    }

    const u16* kfb = kfrag + ((size_t)h * 64 * 12) * 512 + lane * 8;
    const u16* vfb = vfrag + ((size_t)h * 64 * 8) * 512 + lane * 8;

    f32x16 oa[4] = {};
    float mrun = -3.0e38f, lrun = 0.f;

    bf16x8 kcur[12];
    {
        int psub = (s_lo < s_hi) ? s_lo : (n - 1);
        const u16* kp = kfb + (size_t)psub * 12 * 512;
        #pragma unroll
        for (int kk = 0; kk < 12; ++kk)
            kcur[kk] = *(const bf16x8*)(kp + kk * 512);
    }

    for (int sub = s_lo; sub < s_hi; ++sub) {
        f32x16 s0 = {}, s1 = {};
        __builtin_amdgcn_s_setprio(1);
        #pragma unroll
        for (int kk = 0; kk < 12; kk += 2) {
            s0 = __builtin_amdgcn_mfma_f32_32x32x16_bf16(kcur[kk], qfr[kk], s0, 0, 0, 0);
            s1 = __builtin_amdgcn_mfma_f32_32x32x16_bf16(kcur[kk + 1], qfr[kk + 1], s1, 0, 0, 0);
        }
        __builtin_amdgcn_s_setprio(0);
        {
            int nsub = (sub + 1 < s_hi) ? sub + 1 : sub;
            const u16* kp = kfb + (size_t)nsub * 12 * 512;
            #pragma unroll
            for (int kk = 0; kk < 12; ++kk)
                kcur[kk] = *(const bf16x8*)(kp + kk * 512);
        }
        bf16x8 va[8];
        {
            const u16* vp = vfb + (size_t)sub * 8 * 512;
            #pragma unroll
            for (int fi = 0; fi < 8; ++fi)
                va[fi] = *(const bf16x8*)(vp + fi * 512);
        }
        f32x16 sv = s0 + s1;
        if (sub == t) {
            #pragma unroll
            for (int r = 0; r < 16; ++r) {
                int krow = (r & 3) + 8 * (r >> 2) + 4 * hi;
                if (krow > lq) sv[r] = -3.0e38f;
            }
        }
        float tm = sv[0];
        #pragma unroll
        for (int r = 1; r < 16; ++r) tm = fmaxf(tm, sv[r]);
        tm = fmaxf(tm, __shfl_xor(tm, 32, 64));
        if (!__all(tm - mrun <= 8.f)) {
            float mn = fmaxf(mrun, tm);
            float scl = exp2f((mrun - mn) * LOG2E);
            mrun = mn;
            lrun *= scl;
            #pragma unroll
            for (int bb = 0; bb < 4; ++bb)
                #pragma unroll
                for (int r = 0; r < 16; ++r) oa[bb][r] *= scl;
        }
        float p[16];
        float psum = 0.f;
        #pragma unroll
        for (int r = 0; r < 16; ++r) {
            p[r] = exp2f((sv[r] - mrun) * LOG2E);
            psum += p[r];
        }
        psum += __shfl_xor(psum, 32, 64);
        lrun += psum;
        u32 pw[8], sw[8];
        #pragma unroll
        for (int i = 0; i < 8; ++i)
            pw[i] = (u32)f2bf(p[2 * i]) | ((u32)f2bf(p[2 * i + 1]) << 16);
        #pragma unroll
        for (int i = 0; i < 8; ++i)
            sw[i] = (u32)__shfl_xor((int)pw[i], 32, 64);
        union { u32 w[4]; bf16x8 v; } bf0, bf1;
        bf0.w[0] = hi ? sw[2] : pw[0];
        bf0.w[1] = hi ? sw[3] : pw[1];
        bf0.w[2] = hi ? pw[2] : sw[0];
        bf0.w[3] = hi ? pw[3] : sw[1];
        bf1.w[0] = hi ? sw[6] : pw[4];
        bf1.w[1] = hi ? sw[7] : pw[5];
        bf1.w[2] = hi ? pw[6] : sw[4];
        bf1.w[3] = hi ? pw[7] : sw[5];
        __builtin_amdgcn_s_setprio(1);
        #pragma unroll
        for (int bb = 0; bb < 4; ++bb) {
            oa[bb] = __builtin_amdgcn_mfma_f32_32x32x16_bf16(va[bb * 2],     bf0.v, oa[bb], 0, 0, 0);
            oa[bb] = __builtin_amdgcn_mfma_f32_32x32x16_bf16(va[bb * 2 + 1], bf1.v, oa[bb], 0, 0, 0);
        }
        __builtin_amdgcn_s_setprio(0);
    }

    if (half) {
        #pragma unroll
        for (int bb = 0; bb < 4; ++bb)
            #pragma unroll
            for (int r = 0; r < 16; ++r) {
                int dv = bb * 32 + (r & 3) + 8 * (r >> 2) + 4 * hi;
                OB[pr][dv][lq] = oa[bb][r];
            }
        if (lane < 32) {
            MB[pr][0][lane] = mrun;
            MB[pr][1][lane] = lrun;
        }
    }
    __syncthreads();
    if (!half) {
        float mB = MB[pr][0][lq];
        float lB = MB[pr][1][lq];
        float M = fmaxf(mrun, mB);
        float eA = exp2f((mrun - M) * LOG2E);
        float eB = exp2f((mB - M) * LOG2E);
        float L = lrun * eA + lB * eB;
        float inv = 1.0f / L;
        u16* ob = attn + (size_t)(q0 + lq) * (NHEAD * V_D) + h * V_D;
        #pragma unroll
        for (int bb = 0; bb < 4; ++bb)
            #pragma unroll
            for (int rq = 0; rq < 4; ++rq) {
                u16x4 pk;
                #pragma unroll
                for (int rb = 0; rb < 4; ++rb) {
                    int r = rq * 4 + rb;
                    int dv = bb * 32 + rb + 8 * rq + 4 * hi;
                    float o = (oa[bb][r] * eA + OB[pr][dv][lq] * eB) * inv;
                    pk[rb] = f2bf(o);
                }
                *(u16x4*)(ob + bb * 32 + 8 * rq + 4 * hi) = pk;
            }
    }
}

extern "C" void kernel_launch(void* const* d_in, const int* in_sizes, int n_in,
                              void* d_out, int out_size, void* d_ws, size_t ws_size,
                              hipStream_t stream) {
    const float* hs    = (const float*)d_in[0];
    const float* wq_a  = (const float*)d_in[1];
    const float* sq_a  = (const float*)d_in[2];
    const float* wq_b  = (const float*)d_in[3];
    const float* sq_b  = (const float*)d_in[4];
    const float* wkv_a = (const float*)d_in[5];
    const float* skv_a = (const float*)d_in[6];
    const float* wkv_b = (const float*)d_in[7];
    const float* skv_b = (const float*)d_in[8];
    const float* wo    = (const float*)d_in[9];
    const float* so    = (const float*)d_in[10];
    const float* q_ln  = (const float*)d_in[11];
    const float* kv_ln = (const float*)d_in[12];
    const float* cosb  = (const float*)d_in[13];
    const float* sinb  = (const float*)d_in[14];
    float* out = (float*)d_out;

    char* ws = (char*)d_ws;
    size_t off = 0;
    auto alloc = [&](size_t bytes) -> void* {
        void* p = ws + off; off += (bytes + 255) & ~(size_t)255; return p;
    };
    u16* hs_bf  = (u16*)alloc((size_t)S_LEN * HIDDEN * 2);
    u16* lqn    = (u16*)alloc((size_t)S_LEN * QLORA * 2);
    u16* kvn    = (u16*)alloc((size_t)S_LEN * KVLORA * 2);
    u16* kpe    = (u16*)alloc((size_t)S_LEN * ROPE_D * 2);
    u16* kvb    = (u16*)alloc((size_t)S_LEN * NHEAD * 256 * 2);
    u16* attn   = (u16*)alloc((size_t)S_LEN * NHEAD * V_D * 2);
    u16* qfrag  = (u16*)alloc((size_t)NHEAD * 64 * 12 * 512 * 2);
    u16* kfrag  = (u16*)alloc((size_t)NHEAD * 64 * 12 * 512 * 2);
    u16* vfrag  = (u16*)alloc((size_t)NHEAD * 64 * 8 * 512 * 2);
    u16* wcomb  = (u16*)alloc((size_t)NCOMB * HIDDEN * 2);                 // rows: wq_a(1536) + wkv_a(576) + 64 pad
    u16* wqb_bf  = (u16*)alloc((size_t)(NHEAD * HEAD_D) * QLORA * 2);
    u16* wkvb_bf = (u16*)alloc((size_t)(NHEAD * 256) * KVLORA * 2);
    u16* wo_bf   = (u16*)alloc((size_t)HIDDEN * (NHEAD * V_D) * 2);
    float* arena = (float*)alloc((size_t)2 * S_LEN * (NHEAD * HEAD_D) * 4); // 50.3 MB, reused 3x

    cvt_f32_bf16<<<(S_LEN * HIDDEN / 4 + 255) / 256, 256, 0, stream>>>(hs, hs_bf, S_LEN * HIDDEN);

    dequant_w<<<dim3(HIDDEN / 512, QLORA), 64, 0, stream>>>(wq_a, sq_a, wcomb, QLORA, HIDDEN, 16);
    dequant_w<<<dim3(HIDDEN / 512, KVLORA + ROPE_D), 64, 0, stream>>>(wkv_a, skv_a,
        wcomb + (size_t)QLORA * HIDDEN, KVLORA + ROPE_D, HIDDEN, 16);
    dequant_w<<<dim3(QLORA / 512, NHEAD * HEAD_D), 64, 0, stream>>>(wq_b, sq_b, wqb_bf, NHEAD * HEAD_D, QLORA, 12);
    dequant_w<<<dim3(KVLORA / 512, NHEAD * 256), 64, 0, stream>>>(wkv_b, skv_b, wkvb_bf, NHEAD * 256, KVLORA, 4);
    dequant_w<<<dim3((NHEAD * V_D) / 512, HIDDEN), 64, 0, stream>>>(wo, so, wo_bf, HIDDEN, NHEAD * V_D, 16);

    // comb = hs @ [wq_a; wkv_a]^T  [2048 x 2176], split-K=2 -> f32 partials
    gemm_bf16<<<dim3(NCOMB / 128, S_LEN / 128, 2), 256, 0, stream>>>(hs_bf, wcomb, arena,
        S_LEN, NCOMB, HIDDEN, HIDDEN / 2, 2);
    reduce_rms_comb<<<S_LEN, 256, 0, stream>>>(arena, q_ln, kv_ln, lqn, kvn, kpe);

    // qh = lqn @ wq_b^T  [2048 x 3072], split-K=2 -> partials, reduced inside prep_q
    gemm_bf16<<<dim3(NHEAD * HEAD_D / 128, S_LEN / 128, 2), 256, 0, stream>>>(lqn, wqb_bf, arena,
        S_LEN, NHEAD * HEAD_D, QLORA, QLORA / 2, 2);
    prep_q_frag_red<<<dim3(64, NHEAD), 256, 0, stream>>>(arena, cosb, sinb, qfrag);

    // kvb = kvn @ wkv_b^T  [2048 x 4096], K=512: no split
    gemm_bf16<<<dim3(NHEAD * 256 / 128, S_LEN / 128, 1), 256, 0, stream>>>(kvn, wkvb_bf, kvb,
        S_LEN, NHEAD * 256, KVLORA, KVLORA, 1);

    prep_k_frag<<<dim3(64, NHEAD), 256, 0, stream>>>(kvb, kpe, cosb, sinb, kfrag);
    prep_v_frag<<<dim3(64, NHEAD), 256, 0, stream>>>(kvb, vfrag);

    flash_attn2<<<512, 256, 0, stream>>>(qfrag, kfrag, vfrag, attn);

    // out = attn @ wo^T  [2048 x 2048], split-K=2 -> partials -> f32 reduce
    gemm_bf16<<<dim3(HIDDEN / 128, S_LEN / 128, 2), 256, 0, stream>>>(attn, wo_bf, arena,
        S_LEN, HIDDEN, NHEAD * V_D, (NHEAD * V_D) / 2, 2);
    reduce_out<<<(S_LEN * HIDDEN / 4 + 255) / 256, 256, 0, stream>>>(arena, out, S_LEN * HIDDEN);
}